// Round 1
// baseline (852.816 us; speedup 1.0000x reference)
//
#include <hip/hip_runtime.h>
#include <hip/hip_bf16.h>
#include <cmath>

// ---------------------------------------------------------------------------
// GCN: 3x GCNConv (64->128->128->128, no inter-conv activation) -> concat(384)
//      -> Linear(384,384)+ReLU -> Linear(384,2) -> (logits, softmax)
// Strategy (round 1, fp32 everywhere):
//   1. CSR build: per-dst histogram -> single-block scan -> fill (atomics only
//      in build; aggregation itself is atomic-free & deterministic).
//   2. Per conv: dense GEMM xw = A@W (W staged in LDS), then per-node wave
//      aggregation: out[v] = dinv[v]*(sum_e dinv[s]*xw[s] + dinv[v]*xw[v]) + b
//   3. linear1: classic 128x64x32 LDS-tiled fp32 GEMM with B^T semantics + ReLU
//   4. linear2 + softmax fused, wave per node.
// ---------------------------------------------------------------------------

__launch_bounds__(256)
__global__ void init_kernel(int* __restrict__ cnt, int* __restrict__ fill, int n) {
    int i = blockIdx.x * 256 + threadIdx.x;
    if (i < n) { cnt[i] = 1; fill[i] = 0; }   // cnt starts at 1: self-loop
}

__launch_bounds__(256)
__global__ void hist_kernel(const int* __restrict__ dst, int* __restrict__ cnt, int e) {
    int i = blockIdx.x * 256 + threadIdx.x;
    if (i < e) atomicAdd(&cnt[dst[i]], 1);
}

__launch_bounds__(1024)
__global__ void scan_kernel(const int* __restrict__ cnt, int* __restrict__ rp,
                            float* __restrict__ dinv, int n, int etot) {
    __shared__ int sums[1024];
    int t = threadIdx.x;
    int per = (n + 1023) >> 10;
    int start = t * per;
    int end = start + per; if (end > n) end = n;
    int s = 0;
    for (int i = start; i < end; ++i) s += cnt[i] - 1;   // edges excl. self-loop
    sums[t] = s;
    __syncthreads();
    for (int offd = 1; offd < 1024; offd <<= 1) {
        int v = (t >= offd) ? sums[t - offd] : 0;
        __syncthreads();
        sums[t] += v;
        __syncthreads();
    }
    int base = (t > 0) ? sums[t - 1] : 0;
    for (int i = start; i < end; ++i) {
        rp[i] = base;
        base += cnt[i] - 1;
        dinv[i] = rsqrtf((float)cnt[i]);
    }
    if (t == 0) rp[n] = etot;
}

__launch_bounds__(256)
__global__ void fill_kernel(const int* __restrict__ src, const int* __restrict__ dst,
                            const int* __restrict__ rp, int* __restrict__ fill,
                            int* __restrict__ col, int e) {
    int i = blockIdx.x * 256 + threadIdx.x;
    if (i < e) {
        int d = dst[i];
        int pos = rp[d] + atomicAdd(&fill[d], 1);
        col[pos] = src[i];
    }
}

// C[n x 128] = A[n x KIN (stride sA)] @ W[KIN x 128]. W staged in LDS in
// 64-row k-tiles (32 KB). Block: 256 thr, 128 rows; thread: 2 rows x 32 cols.
template<int KIN>
__launch_bounds__(256)
__global__ void gemm_conv(const float* __restrict__ A, int sA,
                          const float* __restrict__ W,
                          float* __restrict__ out, int n) {
    __shared__ float Ws[64 * 128];
    int t  = threadIdx.x;
    int r0 = blockIdx.x * 128 + (t & 63);
    int r1 = r0 + 64;
    int c0 = (t >> 6) * 32;
    int r0c = r0 < n ? r0 : n - 1;
    int r1c = r1 < n ? r1 : n - 1;
    const float* A0 = A + (size_t)r0c * sA;
    const float* A1 = A + (size_t)r1c * sA;
    float acc0[32], acc1[32];
#pragma unroll
    for (int i = 0; i < 32; ++i) { acc0[i] = 0.f; acc1[i] = 0.f; }

    for (int kt = 0; kt < KIN; kt += 64) {
        __syncthreads();
        const float4* Wg  = (const float4*)(W + (size_t)kt * 128);
        float4*       WsV = (float4*)Ws;
#pragma unroll
        for (int i = 0; i < 8; ++i) WsV[t + 256 * i] = Wg[t + 256 * i];
        __syncthreads();
        for (int k0 = 0; k0 < 64; k0 += 4) {
            float4 a0 = *(const float4*)(A0 + kt + k0);
            float4 a1 = *(const float4*)(A1 + kt + k0);
#pragma unroll
            for (int kk = 0; kk < 4; ++kk) {
                float av0 = (&a0.x)[kk];
                float av1 = (&a1.x)[kk];
                const float4* wrow = (const float4*)(Ws + (k0 + kk) * 128 + c0);
#pragma unroll
                for (int c4 = 0; c4 < 8; ++c4) {
                    float4 w = wrow[c4];
                    acc0[c4*4+0] += av0 * w.x; acc0[c4*4+1] += av0 * w.y;
                    acc0[c4*4+2] += av0 * w.z; acc0[c4*4+3] += av0 * w.w;
                    acc1[c4*4+0] += av1 * w.x; acc1[c4*4+1] += av1 * w.y;
                    acc1[c4*4+2] += av1 * w.z; acc1[c4*4+3] += av1 * w.w;
                }
            }
        }
    }
    if (r0 < n) {
        float4* o = (float4*)(out + (size_t)r0 * 128 + c0);
#pragma unroll
        for (int c4 = 0; c4 < 8; ++c4)
            o[c4] = make_float4(acc0[c4*4], acc0[c4*4+1], acc0[c4*4+2], acc0[c4*4+3]);
    }
    if (r1 < n) {
        float4* o = (float4*)(out + (size_t)r1 * 128 + c0);
#pragma unroll
        for (int c4 = 0; c4 < 8; ++c4)
            o[c4] = make_float4(acc1[c4*4], acc1[c4*4+1], acc1[c4*4+2], acc1[c4*4+3]);
    }
}

// One wave per node; lane handles 2 of 128 columns. out points at hcat+colOff.
__launch_bounds__(256)
__global__ void aggregate(const float* __restrict__ xw, const int* __restrict__ rp,
                          const int* __restrict__ col, const float* __restrict__ dinv,
                          const float* __restrict__ bias, float* __restrict__ out,
                          int outStride, int n) {
    int gid  = blockIdx.x * 256 + threadIdx.x;
    int v    = gid >> 6;
    int lane = gid & 63;
    if (v >= n) return;
    float di = dinv[v];
    int b = rp[v], e = rp[v + 1];
    float ax = 0.f, ay = 0.f;
    for (int j = b; j < e; ++j) {
        int s = col[j];
        float ds = dinv[s];
        float2 m = *(const float2*)(xw + (size_t)s * 128 + lane * 2);
        ax += ds * m.x; ay += ds * m.y;
    }
    float2 mv = *(const float2*)(xw + (size_t)v * 128 + lane * 2);
    ax = di * (ax + di * mv.x);
    ay = di * (ay + di * mv.y);
    float2 bb = *(const float2*)(bias + lane * 2);
    *(float2*)(out + (size_t)v * outStride + lane * 2) = make_float2(ax + bb.x, ay + bb.y);
}

// hrel = relu(hcat[n x 384] @ lW1^T + lb1); lW1 is [384 out][384 in] row-major,
// so C[r][o] = dot(A row r, B row o). Tile: 128 rows x 64 outs x 32 k.
__launch_bounds__(256)
__global__ void linear1_relu(const float* __restrict__ A, const float* __restrict__ B,
                             const float* __restrict__ bias, float* __restrict__ outp, int n) {
    __shared__ float As[32][128];
    __shared__ float Bs[32][64];
    int t = threadIdx.x;
    int rowBase = blockIdx.x * 128;
    int oBase   = blockIdx.y * 64;

    int ra = t & 127, ha = t >> 7;          // A stage: row, k-half
    int rb = t & 63,  hb = t >> 6;          // B stage: out-row, k-quarter
    int rowA = rowBase + ra; if (rowA > n - 1) rowA = n - 1;
    const float* Ap = A + (size_t)rowA * 384;
    const float* Bp = B + (size_t)(oBase + rb) * 384;

    int r0 = t & 63, r1 = r0 + 64;
    int c0 = (t >> 6) * 16;
    float acc[2][16];
#pragma unroll
    for (int i = 0; i < 2; ++i)
#pragma unroll
        for (int c = 0; c < 16; ++c) acc[i][c] = 0.f;

    for (int k0 = 0; k0 < 384; k0 += 32) {
        __syncthreads();
#pragma unroll
        for (int j = 0; j < 4; ++j) {
            float4 v = *(const float4*)(Ap + k0 + ha * 16 + j * 4);
            int kk = ha * 16 + j * 4;
            As[kk + 0][ra] = v.x; As[kk + 1][ra] = v.y;
            As[kk + 2][ra] = v.z; As[kk + 3][ra] = v.w;
        }
#pragma unroll
        for (int j = 0; j < 2; ++j) {
            float4 v = *(const float4*)(Bp + k0 + hb * 8 + j * 4);
            int kk = hb * 8 + j * 4;
            Bs[kk + 0][rb] = v.x; Bs[kk + 1][rb] = v.y;
            Bs[kk + 2][rb] = v.z; Bs[kk + 3][rb] = v.w;
        }
        __syncthreads();
#pragma unroll
        for (int kk = 0; kk < 32; ++kk) {
            float a0 = As[kk][r0];
            float a1 = As[kk][r1];
#pragma unroll
            for (int c4 = 0; c4 < 4; ++c4) {
                float4 b4 = *(const float4*)&Bs[kk][c0 + c4 * 4];
                acc[0][c4*4+0] += a0 * b4.x; acc[0][c4*4+1] += a0 * b4.y;
                acc[0][c4*4+2] += a0 * b4.z; acc[0][c4*4+3] += a0 * b4.w;
                acc[1][c4*4+0] += a1 * b4.x; acc[1][c4*4+1] += a1 * b4.y;
                acc[1][c4*4+2] += a1 * b4.z; acc[1][c4*4+3] += a1 * b4.w;
            }
        }
    }
    const float* bp = bias + oBase + c0;
#pragma unroll
    for (int i = 0; i < 2; ++i) {
        int gr = rowBase + (i == 0 ? r0 : r1);
        if (gr < n) {
            float* op = outp + (size_t)gr * 384 + oBase + c0;
#pragma unroll
            for (int c4 = 0; c4 < 4; ++c4) {
                float4 v;
                v.x = fmaxf(acc[i][c4*4+0] + bp[c4*4+0], 0.f);
                v.y = fmaxf(acc[i][c4*4+1] + bp[c4*4+1], 0.f);
                v.z = fmaxf(acc[i][c4*4+2] + bp[c4*4+2], 0.f);
                v.w = fmaxf(acc[i][c4*4+3] + bp[c4*4+3], 0.f);
                ((float4*)op)[c4] = v;
            }
        }
    }
}

// logits = hrel @ lW2^T + lb2 (lW2 is [2][384]); out[0:2N]=logits,
// out[2N:4N]=softmax. One wave per node, butterfly reduce.
__launch_bounds__(256)
__global__ void linear2_softmax(const float* __restrict__ hrel, const float* __restrict__ lW2,
                                const float* __restrict__ lb2, float* __restrict__ out, int n) {
    int gid  = blockIdx.x * 256 + threadIdx.x;
    int node = gid >> 6;
    int lane = gid & 63;
    if (node >= n) return;
    const float* h = hrel + (size_t)node * 384;
    float a0 = 0.f, a1 = 0.f;
#pragma unroll
    for (int j = 0; j < 6; ++j) {
        int k = lane + j * 64;
        float hv = h[k];
        a0 += hv * lW2[k];
        a1 += hv * lW2[384 + k];
    }
#pragma unroll
    for (int off = 32; off > 0; off >>= 1) {
        a0 += __shfl_down(a0, off, 64);
        a1 += __shfl_down(a1, off, 64);
    }
    if (lane == 0) {
        float l0 = a0 + lb2[0], l1 = a1 + lb2[1];
        out[(size_t)node * 2 + 0] = l0;
        out[(size_t)node * 2 + 1] = l1;
        float m  = fmaxf(l0, l1);
        float e0 = expf(l0 - m), e1 = expf(l1 - m);
        float inv = 1.f / (e0 + e1);
        out[(size_t)(n + node) * 2 + 0] = e0 * inv;
        out[(size_t)(n + node) * 2 + 1] = e1 * inv;
    }
}

extern "C" void kernel_launch(void* const* d_in, const int* in_sizes, int n_in,
                              void* d_out, int out_size, void* d_ws, size_t ws_size,
                              hipStream_t stream) {
    const float* x   = (const float*)d_in[0];
    const int*   ei  = (const int*)d_in[1];
    const float* W1  = (const float*)d_in[2];
    const float* b1  = (const float*)d_in[3];
    const float* W2  = (const float*)d_in[4];
    const float* b2  = (const float*)d_in[5];
    const float* W3  = (const float*)d_in[6];
    const float* b3  = (const float*)d_in[7];
    const float* lW1 = (const float*)d_in[8];
    const float* lb1 = (const float*)d_in[9];
    const float* lW2 = (const float*)d_in[10];
    const float* lb2 = (const float*)d_in[11];
    float* out = (float*)d_out;

    int N = in_sizes[0] / 64;
    int E = in_sizes[1] / 2;
    const int* src = ei;
    const int* dst = ei + E;

    char* ws = (char*)d_ws;
    size_t off = 0;
    auto take = [&](size_t bytes) -> char* {
        char* p = ws + off;
        off += (bytes + 255) & ~(size_t)255;
        return p;
    };
    int*   cnt  = (int*)take((size_t)N * 4);
    int*   fill = (int*)take((size_t)N * 4);
    int*   rp   = (int*)take((size_t)(N + 1) * 4);
    float* dinv = (float*)take((size_t)N * 4);
    int*   col  = (int*)take((size_t)E * 4);
    float* xw   = (float*)take((size_t)N * 128 * 4);
    float* hcat = (float*)take((size_t)N * 384 * 4);
    float* hrel = (float*)take((size_t)N * 384 * 4);

    // CSR build
    init_kernel<<<(N + 255) / 256, 256, 0, stream>>>(cnt, fill, N);
    hist_kernel<<<(E + 255) / 256, 256, 0, stream>>>(dst, cnt, E);
    scan_kernel<<<1, 1024, 0, stream>>>(cnt, rp, dinv, N, E);
    fill_kernel<<<(E + 255) / 256, 256, 0, stream>>>(src, dst, rp, fill, col, E);

    int gemmBlocks = (N + 127) / 128;
    int aggBlocks  = (N + 3) / 4;

    // conv1: x[ N x 64 ] @ W1 -> aggregate -> hcat[:, 0:128)
    gemm_conv<64><<<gemmBlocks, 256, 0, stream>>>(x, 64, W1, xw, N);
    aggregate<<<aggBlocks, 256, 0, stream>>>(xw, rp, col, dinv, b1, hcat + 0, 384, N);
    // conv2
    gemm_conv<128><<<gemmBlocks, 256, 0, stream>>>(hcat + 0, 384, W2, xw, N);
    aggregate<<<aggBlocks, 256, 0, stream>>>(xw, rp, col, dinv, b2, hcat + 128, 384, N);
    // conv3
    gemm_conv<128><<<gemmBlocks, 256, 0, stream>>>(hcat + 128, 384, W3, xw, N);
    aggregate<<<aggBlocks, 256, 0, stream>>>(xw, rp, col, dinv, b3, hcat + 256, 384, N);

    // MLP head
    dim3 g1((N + 127) / 128, 6);
    linear1_relu<<<g1, 256, 0, stream>>>(hcat, lW1, lb1, hrel, N);
    linear2_softmax<<<(N + 3) / 4, 256, 0, stream>>>(hrel, lW2, lb2, out, N);
}

// Round 2
// 595.792 us; speedup vs baseline: 1.4314x; 1.4314x over previous
//
#include <hip/hip_runtime.h>
#include <hip/hip_bf16.h>
#include <cmath>

// ---------------------------------------------------------------------------
// Round 2: bf16 MFMA everywhere.
//   - All GEMMs (conv1/2/3, linear1) via mfma_f32_16x16x32_bf16, 128x128 tile,
//     BK=32, LDS row stride 40 bf16 (80 B -> 2-way bank aliasing, free).
//   - xw / hcat / hrel stored bf16: halves edge-gather + GEMM staging bytes.
//   - Conv weights transposed+cast to [out][k] so A and B fragments are both
//     8 contiguous bf16 along k (verified m89/m92 layout: A[m=lane&15][k=quad*8+j],
//     B[k][n=lane&15], C col=lane&15 row=quad*4+reg).
//   - Accumulate fp32 in AGPRs; bias/ReLU in epilogue (linear1) or in the
//     fp32 aggregation (convs).
// ---------------------------------------------------------------------------

typedef __bf16 bf16;
typedef __bf16 bf16x2 __attribute__((ext_vector_type(2)));
typedef __bf16 bf16x8 __attribute__((ext_vector_type(8)));
typedef float  f32x4  __attribute__((ext_vector_type(4)));

// ---------------- CSR build (unchanged from R1) ----------------

__launch_bounds__(256)
__global__ void init_kernel(int* __restrict__ cnt, int* __restrict__ fill, int n) {
    int i = blockIdx.x * 256 + threadIdx.x;
    if (i < n) { cnt[i] = 1; fill[i] = 0; }   // cnt starts at 1: self-loop
}

__launch_bounds__(256)
__global__ void hist_kernel(const int* __restrict__ dst, int* __restrict__ cnt, int e) {
    int i = blockIdx.x * 256 + threadIdx.x;
    if (i < e) atomicAdd(&cnt[dst[i]], 1);
}

__launch_bounds__(1024)
__global__ void scan_kernel(const int* __restrict__ cnt, int* __restrict__ rp,
                            float* __restrict__ dinv, int n, int etot) {
    __shared__ int sums[1024];
    int t = threadIdx.x;
    int per = (n + 1023) >> 10;
    int start = t * per;
    int end = start + per; if (end > n) end = n;
    int s = 0;
    for (int i = start; i < end; ++i) s += cnt[i] - 1;
    sums[t] = s;
    __syncthreads();
    for (int offd = 1; offd < 1024; offd <<= 1) {
        int v = (t >= offd) ? sums[t - offd] : 0;
        __syncthreads();
        sums[t] += v;
        __syncthreads();
    }
    int base = (t > 0) ? sums[t - 1] : 0;
    for (int i = start; i < end; ++i) {
        rp[i] = base;
        base += cnt[i] - 1;
        dinv[i] = rsqrtf((float)cnt[i]);
    }
    if (t == 0) rp[n] = etot;
}

__launch_bounds__(256)
__global__ void fill_kernel(const int* __restrict__ src, const int* __restrict__ dst,
                            const int* __restrict__ rp, int* __restrict__ fill,
                            int* __restrict__ col, int e) {
    int i = blockIdx.x * 256 + threadIdx.x;
    if (i < e) {
        int d = dst[i];
        int pos = rp[d] + atomicAdd(&fill[d], 1);
        col[pos] = src[i];
    }
}

// ---------------- weight / input prep ----------------

__launch_bounds__(256)
__global__ void cast_f32_bf16(const float* __restrict__ in, bf16* __restrict__ out, int n) {
    int i = blockIdx.x * 256 + threadIdx.x;
    if (i < n) out[i] = (bf16)in[i];
}

// W [K][128] fp32 -> Wt [128][K] bf16 (out-major, k contiguous)
__launch_bounds__(256)
__global__ void transpose_cast(const float* __restrict__ W, bf16* __restrict__ Wt, int K) {
    int i = blockIdx.x * 256 + threadIdx.x;
    if (i < K * 128) {
        int k = i >> 7, c = i & 127;
        Wt[c * K + k] = (bf16)W[i];
    }
}

// ---------------- MFMA GEMM ----------------
// C[n x NO] = A_bf16[n x K, strideA] @ Bt_bf16[NO x K]^T   (C[r][o] = dot(A[r], Bt[o]))
// Tile 128x128, BK=32, 256 threads = 4 waves in 2x2 arrangement, each wave 64x64
// as 4x4 frags of 16x16x32. Output bf16 (+ optional bias & ReLU).
template<bool BIAS_RELU>
__launch_bounds__(256)
__global__ void mfma_gemm(const bf16* __restrict__ A, int strideA, int K,
                          const bf16* __restrict__ Bt,
                          const float* __restrict__ bias,
                          bf16* __restrict__ C, int strideC, int n) {
    __shared__ bf16 As[128 * 40];
    __shared__ bf16 Bs[128 * 40];
    int t = threadIdx.x;
    int rowBase = blockIdx.x * 128;
    int colBase = blockIdx.y * 128;

    int lane = t & 63;
    int wv   = t >> 6;
    int wr   = wv >> 1, wc = wv & 1;
    int ml   = lane & 15, quad = lane >> 4;

    f32x4 acc[4][4];
#pragma unroll
    for (int i = 0; i < 4; ++i)
#pragma unroll
        for (int j = 0; j < 4; ++j) acc[i][j] = (f32x4){0.f, 0.f, 0.f, 0.f};

    int sr = t >> 2;            // staging row 0..63 (+64 on second half)
    int sk = (t & 3) * 8;       // staging k offset {0,8,16,24}

    for (int kt = 0; kt < K; kt += 32) {
        __syncthreads();
#pragma unroll
        for (int half = 0; half < 2; ++half) {
            int r  = sr + half * 64;
            int gr = rowBase + r; if (gr >= n) gr = n - 1;
            *(bf16x8*)&As[r * 40 + sk] =
                *(const bf16x8*)(A + (size_t)gr * strideA + kt + sk);
            int br = colBase + r;
            *(bf16x8*)&Bs[r * 40 + sk] =
                *(const bf16x8*)(Bt + (size_t)br * K + kt + sk);
        }
        __syncthreads();
        bf16x8 af[4], bfv[4];
#pragma unroll
        for (int i = 0; i < 4; ++i) {
            af[i]  = *(const bf16x8*)&As[(wr * 64 + i * 16 + ml) * 40 + quad * 8];
            bfv[i] = *(const bf16x8*)&Bs[(wc * 64 + i * 16 + ml) * 40 + quad * 8];
        }
#pragma unroll
        for (int i = 0; i < 4; ++i)
#pragma unroll
            for (int j = 0; j < 4; ++j)
                acc[i][j] = __builtin_amdgcn_mfma_f32_16x16x32_bf16(
                    af[i], bfv[j], acc[i][j], 0, 0, 0);
    }

#pragma unroll
    for (int i = 0; i < 4; ++i) {
#pragma unroll
        for (int reg = 0; reg < 4; ++reg) {
            int gr = rowBase + wr * 64 + i * 16 + quad * 4 + reg;
            if (gr < n) {
#pragma unroll
                for (int j = 0; j < 4; ++j) {
                    int gc = colBase + wc * 64 + j * 16 + ml;
                    float v = acc[i][j][reg];
                    if (BIAS_RELU) v = fmaxf(v + bias[gc], 0.f);
                    C[(size_t)gr * strideC + gc] = (bf16)v;
                }
            }
        }
    }
}

// ---------------- aggregation (bf16 gather, fp32 accumulate) ----------------
// One wave per node; lane handles 2 of 128 columns.
// out[v] = dinv[v]*(sum_e dinv[s]*xw[s] + dinv[v]*xw[v]) + b, written bf16.
__launch_bounds__(256)
__global__ void aggregate(const bf16* __restrict__ xw, const int* __restrict__ rp,
                          const int* __restrict__ col, const float* __restrict__ dinv,
                          const float* __restrict__ bias, bf16* __restrict__ out,
                          int outStride, int n) {
    int gid  = blockIdx.x * 256 + threadIdx.x;
    int v    = gid >> 6;
    int lane = gid & 63;
    if (v >= n) return;
    float di = dinv[v];
    int b = rp[v], e = rp[v + 1];
    float ax = 0.f, ay = 0.f;
    for (int j = b; j < e; ++j) {
        int s = col[j];
        float ds = dinv[s];
        bf16x2 m = *(const bf16x2*)(xw + (size_t)s * 128 + lane * 2);
        ax += ds * (float)m[0]; ay += ds * (float)m[1];
    }
    bf16x2 mv = *(const bf16x2*)(xw + (size_t)v * 128 + lane * 2);
    ax = di * (ax + di * (float)mv[0]);
    ay = di * (ay + di * (float)mv[1]);
    float2 bb = *(const float2*)(bias + lane * 2);
    bf16x2 o;
    o[0] = (bf16)(ax + bb.x);
    o[1] = (bf16)(ay + bb.y);
    *(bf16x2*)(out + (size_t)v * outStride + lane * 2) = o;
}

// ---------------- linear2 + softmax ----------------
__launch_bounds__(256)
__global__ void linear2_softmax(const bf16* __restrict__ hrel, const float* __restrict__ lW2,
                                const float* __restrict__ lb2, float* __restrict__ out, int n) {
    int gid  = blockIdx.x * 256 + threadIdx.x;
    int node = gid >> 6;
    int lane = gid & 63;
    if (node >= n) return;
    const bf16* h = hrel + (size_t)node * 384;
    float a0 = 0.f, a1 = 0.f;
#pragma unroll
    for (int j = 0; j < 6; ++j) {
        int k = lane + j * 64;
        float hv = (float)h[k];
        a0 += hv * lW2[k];
        a1 += hv * lW2[384 + k];
    }
#pragma unroll
    for (int off = 32; off > 0; off >>= 1) {
        a0 += __shfl_down(a0, off, 64);
        a1 += __shfl_down(a1, off, 64);
    }
    if (lane == 0) {
        float l0 = a0 + lb2[0], l1 = a1 + lb2[1];
        out[(size_t)node * 2 + 0] = l0;
        out[(size_t)node * 2 + 1] = l1;
        float m  = fmaxf(l0, l1);
        float e0 = expf(l0 - m), e1 = expf(l1 - m);
        float inv = 1.f / (e0 + e1);
        out[(size_t)(n + node) * 2 + 0] = e0 * inv;
        out[(size_t)(n + node) * 2 + 1] = e1 * inv;
    }
}

extern "C" void kernel_launch(void* const* d_in, const int* in_sizes, int n_in,
                              void* d_out, int out_size, void* d_ws, size_t ws_size,
                              hipStream_t stream) {
    const float* x   = (const float*)d_in[0];
    const int*   ei  = (const int*)d_in[1];
    const float* W1  = (const float*)d_in[2];
    const float* b1  = (const float*)d_in[3];
    const float* W2  = (const float*)d_in[4];
    const float* b2  = (const float*)d_in[5];
    const float* W3  = (const float*)d_in[6];
    const float* b3  = (const float*)d_in[7];
    const float* lW1 = (const float*)d_in[8];
    const float* lb1 = (const float*)d_in[9];
    const float* lW2 = (const float*)d_in[10];
    const float* lb2 = (const float*)d_in[11];
    float* out = (float*)d_out;

    int N = in_sizes[0] / 64;
    int E = in_sizes[1] / 2;
    const int* src = ei;
    const int* dst = ei + E;

    char* ws = (char*)d_ws;
    size_t off = 0;
    auto take = [&](size_t bytes) -> char* {
        char* p = ws + off;
        off += (bytes + 255) & ~(size_t)255;
        return p;
    };
    int*   cnt    = (int*)take((size_t)N * 4);
    int*   fill   = (int*)take((size_t)N * 4);
    int*   rp     = (int*)take((size_t)(N + 1) * 4);
    float* dinv   = (float*)take((size_t)N * 4);
    int*   col    = (int*)take((size_t)E * 4);
    bf16*  x_bf   = (bf16*)take((size_t)N * 64 * 2);
    bf16*  Wt1    = (bf16*)take((size_t)64 * 128 * 2);
    bf16*  Wt2    = (bf16*)take((size_t)128 * 128 * 2);
    bf16*  Wt3    = (bf16*)take((size_t)128 * 128 * 2);
    bf16*  lW1_bf = (bf16*)take((size_t)384 * 384 * 2);
    bf16*  xw     = (bf16*)take((size_t)N * 128 * 2);
    bf16*  hcat   = (bf16*)take((size_t)N * 384 * 2);
    bf16*  hrel   = (bf16*)take((size_t)N * 384 * 2);

    // CSR build
    init_kernel<<<(N + 255) / 256, 256, 0, stream>>>(cnt, fill, N);
    hist_kernel<<<(E + 255) / 256, 256, 0, stream>>>(dst, cnt, E);
    scan_kernel<<<1, 1024, 0, stream>>>(cnt, rp, dinv, N, E);
    fill_kernel<<<(E + 255) / 256, 256, 0, stream>>>(src, dst, rp, fill, col, E);

    // prep: casts + transposes (tiny)
    cast_f32_bf16<<<(N * 64 + 255) / 256, 256, 0, stream>>>(x, x_bf, N * 64);
    transpose_cast<<<(64 * 128 + 255) / 256, 256, 0, stream>>>(W1, Wt1, 64);
    transpose_cast<<<(128 * 128 + 255) / 256, 256, 0, stream>>>(W2, Wt2, 128);
    transpose_cast<<<(128 * 128 + 255) / 256, 256, 0, stream>>>(W3, Wt3, 128);
    cast_f32_bf16<<<(384 * 384 + 255) / 256, 256, 0, stream>>>(lW1, lW1_bf, 384 * 384);

    int gemmBlocks = (N + 127) / 128;
    int aggBlocks  = (N + 3) / 4;

    // conv1
    mfma_gemm<false><<<dim3(gemmBlocks, 1), 256, 0, stream>>>(
        x_bf, 64, 64, Wt1, nullptr, xw, 128, N);
    aggregate<<<aggBlocks, 256, 0, stream>>>(xw, rp, col, dinv, b1, hcat + 0, 384, N);
    // conv2
    mfma_gemm<false><<<dim3(gemmBlocks, 1), 256, 0, stream>>>(
        hcat + 0, 384, 128, Wt2, nullptr, xw, 128, N);
    aggregate<<<aggBlocks, 256, 0, stream>>>(xw, rp, col, dinv, b2, hcat + 128, 384, N);
    // conv3
    mfma_gemm<false><<<dim3(gemmBlocks, 1), 256, 0, stream>>>(
        hcat + 128, 384, 128, Wt3, nullptr, xw, 128, N);
    aggregate<<<aggBlocks, 256, 0, stream>>>(xw, rp, col, dinv, b3, hcat + 256, 384, N);

    // MLP head
    mfma_gemm<true><<<dim3(gemmBlocks, 3), 256, 0, stream>>>(
        hcat, 384, 384, lW1_bf, lb1, hrel, 384, N);
    linear2_softmax<<<(N + 3) / 4, 256, 0, stream>>>(hrel, lW2, lb2, out, N);
}

// Round 3
// 382.616 us; speedup vs baseline: 2.2289x; 1.5572x over previous
//
#include <hip/hip_runtime.h>
#include <hip/hip_bf16.h>
#include <cmath>

// ---------------------------------------------------------------------------
// Round 3:
//   - Device-wide 3-stage scan replaces the 108 us single-block scan_kernel.
//   - Conv GEMM epilogue pre-scales rows by dinv[row] (xs = dinv*xW), so the
//     aggregate loop is a pure gather-sum: out[v]=dinv[v]*(sum xs + xs[v])+b.
//   - Aggregate gather loop unrolled x4 for MLP.
// (From R2: all GEMMs bf16 MFMA 128x128/BK32, bf16 activations.)
// ---------------------------------------------------------------------------

typedef __bf16 bf16;
typedef __bf16 bf16x2 __attribute__((ext_vector_type(2)));
typedef __bf16 bf16x8 __attribute__((ext_vector_type(8)));
typedef float  f32x4  __attribute__((ext_vector_type(4)));

// ---------------- CSR build ----------------

__launch_bounds__(256)
__global__ void init_kernel(int* __restrict__ cnt, int* __restrict__ fill, int n) {
    int i = blockIdx.x * 256 + threadIdx.x;
    if (i < n) { cnt[i] = 1; fill[i] = 0; }   // cnt starts at 1: self-loop
}

__launch_bounds__(256)
__global__ void hist_kernel(const int* __restrict__ dst, int* __restrict__ cnt, int e) {
    int i = blockIdx.x * 256 + threadIdx.x;
    if (i < e) atomicAdd(&cnt[dst[i]], 1);
}

// stage 1: per-block sum of (cnt[i]-1)
__launch_bounds__(256)
__global__ void block_reduce(const int* __restrict__ cnt, int* __restrict__ bsum, int n) {
    __shared__ int s[256];
    int t = threadIdx.x;
    int i = blockIdx.x * 256 + t;
    int v = (i < n) ? cnt[i] - 1 : 0;
    s[t] = v;
    __syncthreads();
#pragma unroll
    for (int off = 128; off > 0; off >>= 1) {
        if (t < off) s[t] += s[t + off];
        __syncthreads();
    }
    if (t == 0) bsum[blockIdx.x] = s[0];
}

// stage 2: single-block exclusive scan of <=256 block sums
__launch_bounds__(256)
__global__ void scan_bsums(int* __restrict__ bsum, int nb) {
    __shared__ int s[256];
    int t = threadIdx.x;
    int v = (t < nb) ? bsum[t] : 0;
    s[t] = v;
    __syncthreads();
#pragma unroll
    for (int off = 1; off < 256; off <<= 1) {
        int tmp = (t >= off) ? s[t - off] : 0;
        __syncthreads();
        s[t] += tmp;
        __syncthreads();
    }
    if (t < nb) bsum[t] = s[t] - v;   // exclusive
}

// stage 3: per-block exclusive scan + global offset -> rp; also dinv
__launch_bounds__(256)
__global__ void write_rp(const int* __restrict__ cnt, const int* __restrict__ bsum,
                         int* __restrict__ rp, float* __restrict__ dinv, int n, int etot) {
    __shared__ int s[256];
    int t = threadIdx.x;
    int i = blockIdx.x * 256 + t;
    int c = (i < n) ? cnt[i] : 1;
    int v = c - 1;
    s[t] = v;
    __syncthreads();
#pragma unroll
    for (int off = 1; off < 256; off <<= 1) {
        int tmp = (t >= off) ? s[t - off] : 0;
        __syncthreads();
        s[t] += tmp;
        __syncthreads();
    }
    if (i < n) {
        rp[i]   = bsum[blockIdx.x] + s[t] - v;
        dinv[i] = rsqrtf((float)c);
        if (i == n - 1) rp[n] = etot;
    }
}

__launch_bounds__(256)
__global__ void fill_kernel(const int* __restrict__ src, const int* __restrict__ dst,
                            const int* __restrict__ rp, int* __restrict__ fill,
                            int* __restrict__ col, int e) {
    int i = blockIdx.x * 256 + threadIdx.x;
    if (i < e) {
        int d = dst[i];
        int pos = rp[d] + atomicAdd(&fill[d], 1);
        col[pos] = src[i];
    }
}

// ---------------- weight / input prep ----------------

__launch_bounds__(256)
__global__ void cast_f32_bf16(const float* __restrict__ in, bf16* __restrict__ out, int n) {
    int i = blockIdx.x * 256 + threadIdx.x;
    if (i < n) out[i] = (bf16)in[i];
}

// W [K][128] fp32 -> Wt [128][K] bf16 (out-major, k contiguous)
__launch_bounds__(256)
__global__ void transpose_cast(const float* __restrict__ W, bf16* __restrict__ Wt, int K) {
    int i = blockIdx.x * 256 + threadIdx.x;
    if (i < K * 128) {
        int k = i >> 7, c = i & 127;
        Wt[c * K + k] = (bf16)W[i];
    }
}

// ---------------- MFMA GEMM ----------------
// C[n x NO] = A_bf16[n x K, strideA] @ Bt_bf16[NO x K]^T.
// Tile 128x128, BK=32, 4 waves 2x2, each wave 64x64 = 4x4 frags of 16x16x32.
// Epilogue: optional bias+ReLU, optional per-row scale (dinv).
template<bool BIAS_RELU>
__launch_bounds__(256)
__global__ void mfma_gemm(const bf16* __restrict__ A, int strideA, int K,
                          const bf16* __restrict__ Bt,
                          const float* __restrict__ bias,
                          const float* __restrict__ rowScale,
                          bf16* __restrict__ C, int strideC, int n) {
    __shared__ bf16 As[128 * 40];
    __shared__ bf16 Bs[128 * 40];
    int t = threadIdx.x;
    int rowBase = blockIdx.x * 128;
    int colBase = blockIdx.y * 128;

    int lane = t & 63;
    int wv   = t >> 6;
    int wr   = wv >> 1, wc = wv & 1;
    int ml   = lane & 15, quad = lane >> 4;

    f32x4 acc[4][4];
#pragma unroll
    for (int i = 0; i < 4; ++i)
#pragma unroll
        for (int j = 0; j < 4; ++j) acc[i][j] = (f32x4){0.f, 0.f, 0.f, 0.f};

    int sr = t >> 2;            // staging row 0..63 (+64 on second half)
    int sk = (t & 3) * 8;       // staging k offset {0,8,16,24}

    for (int kt = 0; kt < K; kt += 32) {
        __syncthreads();
#pragma unroll
        for (int half = 0; half < 2; ++half) {
            int r  = sr + half * 64;
            int gr = rowBase + r; if (gr >= n) gr = n - 1;
            *(bf16x8*)&As[r * 40 + sk] =
                *(const bf16x8*)(A + (size_t)gr * strideA + kt + sk);
            int br = colBase + r;
            *(bf16x8*)&Bs[r * 40 + sk] =
                *(const bf16x8*)(Bt + (size_t)br * K + kt + sk);
        }
        __syncthreads();
        bf16x8 af[4], bfv[4];
#pragma unroll
        for (int i = 0; i < 4; ++i) {
            af[i]  = *(const bf16x8*)&As[(wr * 64 + i * 16 + ml) * 40 + quad * 8];
            bfv[i] = *(const bf16x8*)&Bs[(wc * 64 + i * 16 + ml) * 40 + quad * 8];
        }
#pragma unroll
        for (int i = 0; i < 4; ++i)
#pragma unroll
            for (int j = 0; j < 4; ++j)
                acc[i][j] = __builtin_amdgcn_mfma_f32_16x16x32_bf16(
                    af[i], bfv[j], acc[i][j], 0, 0, 0);
    }

#pragma unroll
    for (int i = 0; i < 4; ++i) {
#pragma unroll
        for (int reg = 0; reg < 4; ++reg) {
            int gr = rowBase + wr * 64 + i * 16 + quad * 4 + reg;
            if (gr < n) {
                float sc = rowScale ? rowScale[gr] : 1.f;
#pragma unroll
                for (int j = 0; j < 4; ++j) {
                    int gc = colBase + wc * 64 + j * 16 + ml;
                    float v = acc[i][j][reg];
                    if (BIAS_RELU) v = fmaxf(v + bias[gc], 0.f);
                    C[(size_t)gr * strideC + gc] = (bf16)(v * sc);
                }
            }
        }
    }
}

// ---------------- aggregation ----------------
// xs rows are pre-scaled by dinv[src]. One wave per node; lane = 2 of 128 cols.
// out[v] = dinv[v]*(sum_edges xs[col[j]] + xs[v]) + b   (xs[v] has dinv[v] baked)
__launch_bounds__(256)
__global__ void aggregate(const bf16* __restrict__ xs, const int* __restrict__ rp,
                          const int* __restrict__ col, const float* __restrict__ dinv,
                          const float* __restrict__ bias, bf16* __restrict__ out,
                          int outStride, int n) {
    int gid  = blockIdx.x * 256 + threadIdx.x;
    int v    = gid >> 6;
    int lane = gid & 63;
    if (v >= n) return;
    float di = dinv[v];
    int b = rp[v], e = rp[v + 1];
    const bf16* base = xs + lane * 2;
    float ax = 0.f, ay = 0.f;
    int j = b;
    for (; j + 4 <= e; j += 4) {
        int s0 = col[j], s1 = col[j + 1], s2 = col[j + 2], s3 = col[j + 3];
        bf16x2 m0 = *(const bf16x2*)(base + (size_t)s0 * 128);
        bf16x2 m1 = *(const bf16x2*)(base + (size_t)s1 * 128);
        bf16x2 m2 = *(const bf16x2*)(base + (size_t)s2 * 128);
        bf16x2 m3 = *(const bf16x2*)(base + (size_t)s3 * 128);
        ax += ((float)m0[0] + (float)m1[0]) + ((float)m2[0] + (float)m3[0]);
        ay += ((float)m0[1] + (float)m1[1]) + ((float)m2[1] + (float)m3[1]);
    }
    for (; j < e; ++j) {
        int s = col[j];
        bf16x2 m = *(const bf16x2*)(base + (size_t)s * 128);
        ax += (float)m[0]; ay += (float)m[1];
    }
    bf16x2 mv = *(const bf16x2*)(base + (size_t)v * 128);
    ax = di * (ax + (float)mv[0]);
    ay = di * (ay + (float)mv[1]);
    float2 bb = *(const float2*)(bias + lane * 2);
    bf16x2 o;
    o[0] = (bf16)(ax + bb.x);
    o[1] = (bf16)(ay + bb.y);
    *(bf16x2*)(out + (size_t)v * outStride + lane * 2) = o;
}

// ---------------- linear2 + softmax ----------------
__launch_bounds__(256)
__global__ void linear2_softmax(const bf16* __restrict__ hrel, const float* __restrict__ lW2,
                                const float* __restrict__ lb2, float* __restrict__ out, int n) {
    int gid  = blockIdx.x * 256 + threadIdx.x;
    int node = gid >> 6;
    int lane = gid & 63;
    if (node >= n) return;
    const bf16* h = hrel + (size_t)node * 384;
    float a0 = 0.f, a1 = 0.f;
#pragma unroll
    for (int j = 0; j < 6; ++j) {
        int k = lane + j * 64;
        float hv = (float)h[k];
        a0 += hv * lW2[k];
        a1 += hv * lW2[384 + k];
    }
#pragma unroll
    for (int off = 32; off > 0; off >>= 1) {
        a0 += __shfl_down(a0, off, 64);
        a1 += __shfl_down(a1, off, 64);
    }
    if (lane == 0) {
        float l0 = a0 + lb2[0], l1 = a1 + lb2[1];
        out[(size_t)node * 2 + 0] = l0;
        out[(size_t)node * 2 + 1] = l1;
        float m  = fmaxf(l0, l1);
        float e0 = expf(l0 - m), e1 = expf(l1 - m);
        float inv = 1.f / (e0 + e1);
        out[(size_t)(n + node) * 2 + 0] = e0 * inv;
        out[(size_t)(n + node) * 2 + 1] = e1 * inv;
    }
}

extern "C" void kernel_launch(void* const* d_in, const int* in_sizes, int n_in,
                              void* d_out, int out_size, void* d_ws, size_t ws_size,
                              hipStream_t stream) {
    const float* x   = (const float*)d_in[0];
    const int*   ei  = (const int*)d_in[1];
    const float* W1  = (const float*)d_in[2];
    const float* b1  = (const float*)d_in[3];
    const float* W2  = (const float*)d_in[4];
    const float* b2  = (const float*)d_in[5];
    const float* W3  = (const float*)d_in[6];
    const float* b3  = (const float*)d_in[7];
    const float* lW1 = (const float*)d_in[8];
    const float* lb1 = (const float*)d_in[9];
    const float* lW2 = (const float*)d_in[10];
    const float* lb2 = (const float*)d_in[11];
    float* out = (float*)d_out;

    int N = in_sizes[0] / 64;
    int E = in_sizes[1] / 2;
    const int* src = ei;
    const int* dst = ei + E;

    char* ws = (char*)d_ws;
    size_t off = 0;
    auto take = [&](size_t bytes) -> char* {
        char* p = ws + off;
        off += (bytes + 255) & ~(size_t)255;
        return p;
    };
    int nBlk = (N + 255) / 256;
    int*   cnt    = (int*)take((size_t)N * 4);
    int*   fill   = (int*)take((size_t)N * 4);
    int*   rp     = (int*)take((size_t)(N + 1) * 4);
    float* dinv   = (float*)take((size_t)N * 4);
    int*   bsum   = (int*)take((size_t)nBlk * 4);
    int*   col    = (int*)take((size_t)E * 4);
    bf16*  x_bf   = (bf16*)take((size_t)N * 64 * 2);
    bf16*  Wt1    = (bf16*)take((size_t)64 * 128 * 2);
    bf16*  Wt2    = (bf16*)take((size_t)128 * 128 * 2);
    bf16*  Wt3    = (bf16*)take((size_t)128 * 128 * 2);
    bf16*  lW1_bf = (bf16*)take((size_t)384 * 384 * 2);
    bf16*  xw     = (bf16*)take((size_t)N * 128 * 2);
    bf16*  hcat   = (bf16*)take((size_t)N * 384 * 2);
    bf16*  hrel   = (bf16*)take((size_t)N * 384 * 2);

    // CSR build (scan parallelized: reduce -> scan block sums -> writeback)
    init_kernel<<<nBlk, 256, 0, stream>>>(cnt, fill, N);
    hist_kernel<<<(E + 255) / 256, 256, 0, stream>>>(dst, cnt, E);
    block_reduce<<<nBlk, 256, 0, stream>>>(cnt, bsum, N);
    scan_bsums<<<1, 256, 0, stream>>>(bsum, nBlk);
    write_rp<<<nBlk, 256, 0, stream>>>(cnt, bsum, rp, dinv, N, E);
    fill_kernel<<<(E + 255) / 256, 256, 0, stream>>>(src, dst, rp, fill, col, E);

    // prep: casts + transposes (tiny)
    cast_f32_bf16<<<(N * 64 + 255) / 256, 256, 0, stream>>>(x, x_bf, N * 64);
    transpose_cast<<<(64 * 128 + 255) / 256, 256, 0, stream>>>(W1, Wt1, 64);
    transpose_cast<<<(128 * 128 + 255) / 256, 256, 0, stream>>>(W2, Wt2, 128);
    transpose_cast<<<(128 * 128 + 255) / 256, 256, 0, stream>>>(W3, Wt3, 128);
    cast_f32_bf16<<<(384 * 384 + 255) / 256, 256, 0, stream>>>(lW1, lW1_bf, 384 * 384);

    int gemmBlocks = (N + 127) / 128;
    int aggBlocks  = (N + 3) / 4;

    // conv1 (epilogue scales rows by dinv -> xs)
    mfma_gemm<false><<<dim3(gemmBlocks, 1), 256, 0, stream>>>(
        x_bf, 64, 64, Wt1, nullptr, dinv, xw, 128, N);
    aggregate<<<aggBlocks, 256, 0, stream>>>(xw, rp, col, dinv, b1, hcat + 0, 384, N);
    // conv2
    mfma_gemm<false><<<dim3(gemmBlocks, 1), 256, 0, stream>>>(
        hcat + 0, 384, 128, Wt2, nullptr, dinv, xw, 128, N);
    aggregate<<<aggBlocks, 256, 0, stream>>>(xw, rp, col, dinv, b2, hcat + 128, 384, N);
    // conv3
    mfma_gemm<false><<<dim3(gemmBlocks, 1), 256, 0, stream>>>(
        hcat + 128, 384, 128, Wt3, nullptr, dinv, xw, 128, N);
    aggregate<<<aggBlocks, 256, 0, stream>>>(xw, rp, col, dinv, b3, hcat + 256, 384, N);

    // MLP head
    mfma_gemm<true><<<dim3(gemmBlocks, 3), 256, 0, stream>>>(
        hcat, 384, 384, lW1_bf, lb1, nullptr, hrel, 384, N);
    linear2_softmax<<<(N + 3) / 4, 256, 0, stream>>>(hrel, lW2, lb2, out, N);
}

// Round 4
// 380.579 us; speedup vs baseline: 2.2408x; 1.0054x over previous
//
#include <hip/hip_runtime.h>
#include <hip/hip_bf16.h>
#include <cmath>

// ---------------------------------------------------------------------------
// Round 4:
//   - mfma_gemm staging via global_load_lds width=16 (async, no VGPR trip).
//     LDS layout: linear 16-B chunks, row stride 32 bf16, XOR swizzle
//     chunk' = chunk ^ (row&3) realized by permuting per-lane GLOBAL addrs
//     (LDS dest is wave-uniform base + lane*16). Frag reads 2-way alias = free.
//   - fill_kernel: 4 independent edges/thread (4 atomic chains in flight).
//   - aggregate: x8 unrolled gather.
//   - weight prep fused into one kernel.
// ---------------------------------------------------------------------------

typedef __bf16 bf16;
typedef __bf16 bf16x2 __attribute__((ext_vector_type(2)));
typedef __bf16 bf16x8 __attribute__((ext_vector_type(8)));
typedef float  f32x4  __attribute__((ext_vector_type(4)));

__device__ __forceinline__ void load_lds16(const bf16* g, bf16* l) {
    __builtin_amdgcn_global_load_lds(
        (const __attribute__((address_space(1))) void*)g,
        (__attribute__((address_space(3))) void*)l, 16, 0, 0);
}

// ---------------- CSR build ----------------

__launch_bounds__(256)
__global__ void init_kernel(int* __restrict__ cnt, int* __restrict__ fill, int n) {
    int i = blockIdx.x * 256 + threadIdx.x;
    if (i < n) { cnt[i] = 1; fill[i] = 0; }   // cnt starts at 1: self-loop
}

__launch_bounds__(256)
__global__ void hist_kernel(const int* __restrict__ dst, int* __restrict__ cnt, int e) {
    int i = blockIdx.x * 256 + threadIdx.x;
    if (i < e) atomicAdd(&cnt[dst[i]], 1);
}

__launch_bounds__(256)
__global__ void block_reduce(const int* __restrict__ cnt, int* __restrict__ bsum, int n) {
    __shared__ int s[256];
    int t = threadIdx.x;
    int i = blockIdx.x * 256 + t;
    int v = (i < n) ? cnt[i] - 1 : 0;
    s[t] = v;
    __syncthreads();
#pragma unroll
    for (int off = 128; off > 0; off >>= 1) {
        if (t < off) s[t] += s[t + off];
        __syncthreads();
    }
    if (t == 0) bsum[blockIdx.x] = s[0];
}

__launch_bounds__(256)
__global__ void scan_bsums(int* __restrict__ bsum, int nb) {
    __shared__ int s[256];
    int t = threadIdx.x;
    int v = (t < nb) ? bsum[t] : 0;
    s[t] = v;
    __syncthreads();
#pragma unroll
    for (int off = 1; off < 256; off <<= 1) {
        int tmp = (t >= off) ? s[t - off] : 0;
        __syncthreads();
        s[t] += tmp;
        __syncthreads();
    }
    if (t < nb) bsum[t] = s[t] - v;   // exclusive
}

__launch_bounds__(256)
__global__ void write_rp(const int* __restrict__ cnt, const int* __restrict__ bsum,
                         int* __restrict__ rp, float* __restrict__ dinv, int n, int etot) {
    __shared__ int s[256];
    int t = threadIdx.x;
    int i = blockIdx.x * 256 + t;
    int c = (i < n) ? cnt[i] : 1;
    int v = c - 1;
    s[t] = v;
    __syncthreads();
#pragma unroll
    for (int off = 1; off < 256; off <<= 1) {
        int tmp = (t >= off) ? s[t - off] : 0;
        __syncthreads();
        s[t] += tmp;
        __syncthreads();
    }
    if (i < n) {
        rp[i]   = bsum[blockIdx.x] + s[t] - v;
        dinv[i] = rsqrtf((float)c);
        if (i == n - 1) rp[n] = etot;
    }
}

// 4 independent edges per thread -> 4 atomic+store chains in flight
__launch_bounds__(256)
__global__ void fill_kernel(const int* __restrict__ src, const int* __restrict__ dst,
                            const int* __restrict__ rp, int* __restrict__ fill,
                            int* __restrict__ col, int e) {
    int i0 = (blockIdx.x * 256 + threadIdx.x) * 4;
    if (i0 + 4 <= e) {
        int d0 = dst[i0], d1 = dst[i0+1], d2 = dst[i0+2], d3 = dst[i0+3];
        int s0 = src[i0], s1 = src[i0+1], s2 = src[i0+2], s3 = src[i0+3];
        int p0 = rp[d0] + atomicAdd(&fill[d0], 1);
        int p1 = rp[d1] + atomicAdd(&fill[d1], 1);
        int p2 = rp[d2] + atomicAdd(&fill[d2], 1);
        int p3 = rp[d3] + atomicAdd(&fill[d3], 1);
        col[p0] = s0; col[p1] = s1; col[p2] = s2; col[p3] = s3;
    } else {
        for (int i = i0; i < e; ++i) {
            int d = dst[i];
            int pos = rp[d] + atomicAdd(&fill[d], 1);
            col[pos] = src[i];
        }
    }
}

// ---------------- prep ----------------

__launch_bounds__(256)
__global__ void cast_f32_bf16(const float* __restrict__ in, bf16* __restrict__ out, int n) {
    int i = blockIdx.x * 256 + threadIdx.x;
    if (i < n) out[i] = (bf16)in[i];
}

// fused: transpose+cast W1 (64x128), W2, W3 (128x128), cast lW1 (384x384)
__launch_bounds__(256)
__global__ void weight_prep(const float* __restrict__ W1, const float* __restrict__ W2,
                            const float* __restrict__ W3, const float* __restrict__ lW1,
                            bf16* __restrict__ Wt1, bf16* __restrict__ Wt2,
                            bf16* __restrict__ Wt3, bf16* __restrict__ lW1_bf) {
    int i = blockIdx.x * 256 + threadIdx.x;
    if (i < 8192) {
        int k = i >> 7, c = i & 127; Wt1[c * 64 + k] = (bf16)W1[i];
    } else if (i < 24576) {
        int j = i - 8192; int k = j >> 7, c = j & 127; Wt2[c * 128 + k] = (bf16)W2[j];
    } else if (i < 40960) {
        int j = i - 24576; int k = j >> 7, c = j & 127; Wt3[c * 128 + k] = (bf16)W3[j];
    } else if (i < 188416) {
        int j = i - 40960; lW1_bf[j] = (bf16)lW1[j];
    }
}

// ---------------- MFMA GEMM ----------------
// C[n x NO] = A[n x K, strideA] @ Bt[NO x K]^T. Tile 128x128, BK=32, 4 waves
// (2x2, each 64x64 = 4x4 frags of 16x16x32). Staging: global_load_lds x16.
// LDS: 128 rows x 4 chunks of 16 B (8 bf16), chunk swizzle c^(r&3).
template<bool BIAS_RELU>
__launch_bounds__(256, 4)
__global__ void mfma_gemm(const bf16* __restrict__ A, int strideA, int K,
                          const bf16* __restrict__ Bt,
                          const float* __restrict__ bias,
                          const float* __restrict__ rowScale,
                          bf16* __restrict__ C, int strideC, int n) {
    __shared__ bf16 As[128 * 32];
    __shared__ bf16 Bs[128 * 32];
    int t = threadIdx.x;
    int rowBase = blockIdx.x * 128;
    int colBase = blockIdx.y * 128;

    int lane = t & 63;
    int wv   = t >> 6;
    int wr   = wv >> 1, wc = wv & 1;
    int ml   = lane & 15, quad = lane >> 4;

    f32x4 acc[4][4];
#pragma unroll
    for (int i = 0; i < 4; ++i)
#pragma unroll
        for (int j = 0; j < 4; ++j) acc[i][j] = (f32x4){0.f, 0.f, 0.f, 0.f};

    // staging: wave wv covers tile rows [wv*32, wv*32+32) of A and of B.
    // lane's chunk within instr: r = wv*32 + inst*16 + (lane>>2), c = lane&3;
    // global k-chunk = c ^ (r&3)  (so LDS chunk c holds global chunk c^(r&3))
    int srow0 = wv * 32 + (lane >> 2);
    int cchunk = lane & 3;

    for (int kt = 0; kt < K; kt += 32) {
        __syncthreads();
#pragma unroll
        for (int inst = 0; inst < 2; ++inst) {
            int r  = srow0 + inst * 16;
            int gc = (cchunk ^ (r & 3)) * 8;           // bf16 offset in k
            int gr = rowBase + r; if (gr >= n) gr = n - 1;
            load_lds16(A + (size_t)gr * strideA + kt + gc,
                       &As[(wv * 128 + inst * 64) * 8]);
            int br = colBase + r;
            load_lds16(Bt + (size_t)br * K + kt + gc,
                       &Bs[(wv * 128 + inst * 64) * 8]);
        }
        __syncthreads();
        bf16x8 af[4], bfv[4];
#pragma unroll
        for (int i = 0; i < 4; ++i) {
            int ra = wr * 64 + i * 16 + ml;
            int rb = wc * 64 + i * 16 + ml;
            af[i]  = *(const bf16x8*)&As[(ra * 4 + (quad ^ (ra & 3))) * 8];
            bfv[i] = *(const bf16x8*)&Bs[(rb * 4 + (quad ^ (rb & 3))) * 8];
        }
#pragma unroll
        for (int i = 0; i < 4; ++i)
#pragma unroll
            for (int j = 0; j < 4; ++j)
                acc[i][j] = __builtin_amdgcn_mfma_f32_16x16x32_bf16(
                    af[i], bfv[j], acc[i][j], 0, 0, 0);
    }

#pragma unroll
    for (int i = 0; i < 4; ++i) {
#pragma unroll
        for (int reg = 0; reg < 4; ++reg) {
            int gr = rowBase + wr * 64 + i * 16 + quad * 4 + reg;
            if (gr < n) {
                float sc = rowScale ? rowScale[gr] : 1.f;
#pragma unroll
                for (int j = 0; j < 4; ++j) {
                    int gc = colBase + wc * 64 + j * 16 + ml;
                    float v = acc[i][j][reg];
                    if (BIAS_RELU) v = fmaxf(v + bias[gc], 0.f);
                    C[(size_t)gr * strideC + gc] = (bf16)(v * sc);
                }
            }
        }
    }
}

// ---------------- aggregation ----------------
// xs rows pre-scaled by dinv[src]. One wave/node; lane = 2 of 128 cols.
// out[v] = dinv[v]*(sum_edges xs[col[j]] + xs[v]) + b
__launch_bounds__(256)
__global__ void aggregate(const bf16* __restrict__ xs, const int* __restrict__ rp,
                          const int* __restrict__ col, const float* __restrict__ dinv,
                          const float* __restrict__ bias, bf16* __restrict__ out,
                          int outStride, int n) {
    int gid  = blockIdx.x * 256 + threadIdx.x;
    int v    = gid >> 6;
    int lane = gid & 63;
    if (v >= n) return;
    float di = dinv[v];
    int b = rp[v], e = rp[v + 1];
    const bf16* base = xs + lane * 2;
    float ax = 0.f, ay = 0.f;
    int j = b;
    for (; j + 8 <= e; j += 8) {
        bf16x2 m0 = *(const bf16x2*)(base + (size_t)col[j]     * 128);
        bf16x2 m1 = *(const bf16x2*)(base + (size_t)col[j + 1] * 128);
        bf16x2 m2 = *(const bf16x2*)(base + (size_t)col[j + 2] * 128);
        bf16x2 m3 = *(const bf16x2*)(base + (size_t)col[j + 3] * 128);
        bf16x2 m4 = *(const bf16x2*)(base + (size_t)col[j + 4] * 128);
        bf16x2 m5 = *(const bf16x2*)(base + (size_t)col[j + 5] * 128);
        bf16x2 m6 = *(const bf16x2*)(base + (size_t)col[j + 6] * 128);
        bf16x2 m7 = *(const bf16x2*)(base + (size_t)col[j + 7] * 128);
        ax += (((float)m0[0] + (float)m1[0]) + ((float)m2[0] + (float)m3[0]))
            + (((float)m4[0] + (float)m5[0]) + ((float)m6[0] + (float)m7[0]));
        ay += (((float)m0[1] + (float)m1[1]) + ((float)m2[1] + (float)m3[1]))
            + (((float)m4[1] + (float)m5[1]) + ((float)m6[1] + (float)m7[1]));
    }
    for (; j < e; ++j) {
        bf16x2 m = *(const bf16x2*)(base + (size_t)col[j] * 128);
        ax += (float)m[0]; ay += (float)m[1];
    }
    bf16x2 mv = *(const bf16x2*)(base + (size_t)v * 128);
    ax = di * (ax + (float)mv[0]);
    ay = di * (ay + (float)mv[1]);
    float2 bb = *(const float2*)(bias + lane * 2);
    bf16x2 o;
    o[0] = (bf16)(ax + bb.x);
    o[1] = (bf16)(ay + bb.y);
    *(bf16x2*)(out + (size_t)v * outStride + lane * 2) = o;
}

// ---------------- linear2 + softmax ----------------
__launch_bounds__(256)
__global__ void linear2_softmax(const bf16* __restrict__ hrel, const float* __restrict__ lW2,
                                const float* __restrict__ lb2, float* __restrict__ out, int n) {
    int gid  = blockIdx.x * 256 + threadIdx.x;
    int node = gid >> 6;
    int lane = gid & 63;
    if (node >= n) return;
    const bf16* h = hrel + (size_t)node * 384;
    float a0 = 0.f, a1 = 0.f;
#pragma unroll
    for (int j = 0; j < 6; ++j) {
        int k = lane + j * 64;
        float hv = (float)h[k];
        a0 += hv * lW2[k];
        a1 += hv * lW2[384 + k];
    }
#pragma unroll
    for (int off = 32; off > 0; off >>= 1) {
        a0 += __shfl_down(a0, off, 64);
        a1 += __shfl_down(a1, off, 64);
    }
    if (lane == 0) {
        float l0 = a0 + lb2[0], l1 = a1 + lb2[1];
        out[(size_t)node * 2 + 0] = l0;
        out[(size_t)node * 2 + 1] = l1;
        float m  = fmaxf(l0, l1);
        float e0 = expf(l0 - m), e1 = expf(l1 - m);
        float inv = 1.f / (e0 + e1);
        out[(size_t)(n + node) * 2 + 0] = e0 * inv;
        out[(size_t)(n + node) * 2 + 1] = e1 * inv;
    }
}

extern "C" void kernel_launch(void* const* d_in, const int* in_sizes, int n_in,
                              void* d_out, int out_size, void* d_ws, size_t ws_size,
                              hipStream_t stream) {
    const float* x   = (const float*)d_in[0];
    const int*   ei  = (const int*)d_in[1];
    const float* W1  = (const float*)d_in[2];
    const float* b1  = (const float*)d_in[3];
    const float* W2  = (const float*)d_in[4];
    const float* b2  = (const float*)d_in[5];
    const float* W3  = (const float*)d_in[6];
    const float* b3  = (const float*)d_in[7];
    const float* lW1 = (const float*)d_in[8];
    const float* lb1 = (const float*)d_in[9];
    const float* lW2 = (const float*)d_in[10];
    const float* lb2 = (const float*)d_in[11];
    float* out = (float*)d_out;

    int N = in_sizes[0] / 64;
    int E = in_sizes[1] / 2;
    const int* src = ei;
    const int* dst = ei + E;

    char* ws = (char*)d_ws;
    size_t off = 0;
    auto take = [&](size_t bytes) -> char* {
        char* p = ws + off;
        off += (bytes + 255) & ~(size_t)255;
        return p;
    };
    int nBlk = (N + 255) / 256;
    int*   cnt    = (int*)take((size_t)N * 4);
    int*   fill   = (int*)take((size_t)N * 4);
    int*   rp     = (int*)take((size_t)(N + 1) * 4);
    float* dinv   = (float*)take((size_t)N * 4);
    int*   bsum   = (int*)take((size_t)nBlk * 4);
    int*   col    = (int*)take((size_t)E * 4);
    bf16*  x_bf   = (bf16*)take((size_t)N * 64 * 2);
    bf16*  Wt1    = (bf16*)take((size_t)64 * 128 * 2);
    bf16*  Wt2    = (bf16*)take((size_t)128 * 128 * 2);
    bf16*  Wt3    = (bf16*)take((size_t)128 * 128 * 2);
    bf16*  lW1_bf = (bf16*)take((size_t)384 * 384 * 2);
    bf16*  xw     = (bf16*)take((size_t)N * 128 * 2);
    bf16*  hcat   = (bf16*)take((size_t)N * 384 * 2);
    bf16*  hrel   = (bf16*)take((size_t)N * 384 * 2);

    // CSR build
    init_kernel<<<nBlk, 256, 0, stream>>>(cnt, fill, N);
    hist_kernel<<<(E + 255) / 256, 256, 0, stream>>>(dst, cnt, E);
    block_reduce<<<nBlk, 256, 0, stream>>>(cnt, bsum, N);
    scan_bsums<<<1, 256, 0, stream>>>(bsum, nBlk);
    write_rp<<<nBlk, 256, 0, stream>>>(cnt, bsum, rp, dinv, N, E);
    fill_kernel<<<(E + 1023) / 1024, 256, 0, stream>>>(src, dst, rp, fill, col, E);

    // prep
    cast_f32_bf16<<<(N * 64 + 255) / 256, 256, 0, stream>>>(x, x_bf, N * 64);
    weight_prep<<<736, 256, 0, stream>>>(W1, W2, W3, lW1, Wt1, Wt2, Wt3, lW1_bf);

    int gemmBlocks = (N + 127) / 128;
    int aggBlocks  = (N + 3) / 4;

    // conv1 (epilogue scales rows by dinv -> xs)
    mfma_gemm<false><<<dim3(gemmBlocks, 1), 256, 0, stream>>>(
        x_bf, 64, 64, Wt1, nullptr, dinv, xw, 128, N);
    aggregate<<<aggBlocks, 256, 0, stream>>>(xw, rp, col, dinv, b1, hcat + 0, 384, N);
    // conv2
    mfma_gemm<false><<<dim3(gemmBlocks, 1), 256, 0, stream>>>(
        hcat + 0, 384, 128, Wt2, nullptr, dinv, xw, 128, N);
    aggregate<<<aggBlocks, 256, 0, stream>>>(xw, rp, col, dinv, b2, hcat + 128, 384, N);
    // conv3
    mfma_gemm<false><<<dim3(gemmBlocks, 1), 256, 0, stream>>>(
        hcat + 128, 384, 128, Wt3, nullptr, dinv, xw, 128, N);
    aggregate<<<aggBlocks, 256, 0, stream>>>(xw, rp, col, dinv, b3, hcat + 256, 384, N);

    // MLP head
    mfma_gemm<true><<<dim3(gemmBlocks, 3), 256, 0, stream>>>(
        hcat, 384, 384, lW1_bf, lb1, nullptr, hrel, 384, N);
    linear2_softmax<<<(N + 3) / 4, 256, 0, stream>>>(hrel, lW2, lb2, out, N);
}

// Round 5
// 353.351 us; speedup vs baseline: 2.4135x; 1.0771x over previous
//
#include <hip/hip_runtime.h>
#include <hip/hip_bf16.h>
#include <cmath>

// ---------------------------------------------------------------------------
// Round 5:
//   - Binned CSR build replaces scatter fill (was 50 us, 54 MB write-amp):
//     bin_pairs: edges -> 196 buckets (256 dst nodes each) as packed u32
//     (src|dstLow<<16), per-block LDS hist + bulk tail reserve -> run-coalesced
//     writes. csr_fill: one block/bucket, scatter in LDS window (LDS atomics),
//     write col coalesced.
//   - conv1 aggregates BEFORE the GEMM (64-dim rows: half the gather bytes);
//     bias folded into GEMM epilogue.
//   - GEMMs: bf16 MFMA 128x128/BK32, global_load_lds w16, XOR-swizzled LDS.
// ---------------------------------------------------------------------------

typedef __bf16 bf16;
typedef __bf16 bf16x2 __attribute__((ext_vector_type(2)));
typedef __bf16 bf16x8 __attribute__((ext_vector_type(8)));
typedef float  f32x4  __attribute__((ext_vector_type(4)));

__device__ __forceinline__ void load_lds16(const bf16* g, bf16* l) {
    __builtin_amdgcn_global_load_lds(
        (const __attribute__((address_space(1))) void*)g,
        (__attribute__((address_space(3))) void*)l, 16, 0, 0);
}

// ---------------- CSR build ----------------

__launch_bounds__(256)
__global__ void init_kernel(int* __restrict__ cnt, int* __restrict__ fill, int n) {
    int i = blockIdx.x * 256 + threadIdx.x;
    if (i < n) { cnt[i] = 1; fill[i] = 0; }   // cnt starts at 1: self-loop
}

__launch_bounds__(256)
__global__ void hist_kernel(const int* __restrict__ dst, int* __restrict__ cnt, int e) {
    int i = blockIdx.x * 256 + threadIdx.x;
    if (i < e) atomicAdd(&cnt[dst[i]], 1);
}

__launch_bounds__(256)
__global__ void block_reduce(const int* __restrict__ cnt, int* __restrict__ bsum, int n) {
    __shared__ int s[256];
    int t = threadIdx.x;
    int i = blockIdx.x * 256 + t;
    int v = (i < n) ? cnt[i] - 1 : 0;
    s[t] = v;
    __syncthreads();
#pragma unroll
    for (int off = 128; off > 0; off >>= 1) {
        if (t < off) s[t] += s[t + off];
        __syncthreads();
    }
    if (t == 0) bsum[blockIdx.x] = s[0];
}

__launch_bounds__(256)
__global__ void scan_bsums(int* __restrict__ bsum, int nb) {
    __shared__ int s[256];
    int t = threadIdx.x;
    int v = (t < nb) ? bsum[t] : 0;
    s[t] = v;
    __syncthreads();
#pragma unroll
    for (int off = 1; off < 256; off <<= 1) {
        int tmp = (t >= off) ? s[t - off] : 0;
        __syncthreads();
        s[t] += tmp;
        __syncthreads();
    }
    if (t < nb) bsum[t] = s[t] - v;   // exclusive
}

__launch_bounds__(256)
__global__ void write_rp(const int* __restrict__ cnt, const int* __restrict__ bsum,
                         int* __restrict__ rp, float* __restrict__ dinv, int n, int etot) {
    __shared__ int s[256];
    int t = threadIdx.x;
    int i = blockIdx.x * 256 + t;
    int c = (i < n) ? cnt[i] : 1;
    int v = c - 1;
    s[t] = v;
    __syncthreads();
#pragma unroll
    for (int off = 1; off < 256; off <<= 1) {
        int tmp = (t >= off) ? s[t - off] : 0;
        __syncthreads();
        s[t] += tmp;
        __syncthreads();
    }
    if (i < n) {
        rp[i]   = bsum[blockIdx.x] + s[t] - v;
        dinv[i] = rsqrtf((float)c);
        if (i == n - 1) rp[n] = etot;
    }
}

// tails[b] = rp[b*256] (bucket regions tile the col/pairs space exactly)
__launch_bounds__(256)
__global__ void tail_init(const int* __restrict__ rp, int* __restrict__ tail, int nbuck) {
    int t = threadIdx.x;
    if (t < nbuck) tail[t] = rp[t << 8];
}

// Pass 1: bin edges by dst>>8 into per-bucket regions of `pairs`.
// Packed u32 = src | (dst&255)<<16 (requires N <= 65536).
__launch_bounds__(256)
__global__ void bin_pairs(const int* __restrict__ src, const int* __restrict__ dst,
                          int* __restrict__ tail, unsigned int* __restrict__ pairs,
                          int e, int nbuck) {
    __shared__ int hist[256], base[256], cur[256];
    int t = threadIdx.x;
    hist[t] = 0; cur[t] = 0;
    __syncthreads();
    int perBlock = (e + gridDim.x - 1) / gridDim.x;
    int lo = blockIdx.x * perBlock;
    int hi = lo + perBlock; if (hi > e) hi = e;
    for (int i = lo + t; i < hi; i += 256)
        atomicAdd(&hist[dst[i] >> 8], 1);
    __syncthreads();
    if (t < nbuck && hist[t] > 0) base[t] = atomicAdd(&tail[t], hist[t]);
    __syncthreads();
    for (int i = lo + t; i < hi; i += 256) {
        int d = dst[i];
        int b = d >> 8;
        int r = atomicAdd(&cur[b], 1);
        pairs[base[b] + r] = (unsigned)src[i] | ((unsigned)(d & 255) << 16);
    }
}

// Pass 2: one block per bucket; scatter into LDS window, write col coalesced.
#define FILL_CAP 6144
__launch_bounds__(256)
__global__ void csr_fill(const unsigned int* __restrict__ pairs, const int* __restrict__ rp,
                         int* __restrict__ col, int n) {
    __shared__ int rpl[257];
    __shared__ int fillc[256];
    __shared__ int win[FILL_CAP];
    int b = blockIdx.x;
    int t = threadIdx.x;
    int nodeBase = b << 8;
    int nhi = n - nodeBase; if (nhi > 256) nhi = 256;
    for (int i = t; i <= nhi; i += 256) rpl[i] = rp[nodeBase + i];
    fillc[t] = 0;
    __syncthreads();
    int lo = rpl[0], hi = rpl[nhi];
    int cnt = hi - lo;
    if (cnt <= FILL_CAP) {
        for (int i = t; i < cnt; i += 256) {
            unsigned p = pairs[lo + i];
            int dl = (int)(p >> 16);
            int r = atomicAdd(&fillc[dl], 1);
            win[rpl[dl] - lo + r] = (int)(p & 0xffffu);
        }
        __syncthreads();
        for (int i = t; i < cnt; i += 256) col[lo + i] = win[i];
    } else {   // overflow fallback (never taken for random graphs)
        for (int i = t; i < cnt; i += 256) {
            unsigned p = pairs[lo + i];
            int dl = (int)(p >> 16);
            int r = atomicAdd(&fillc[dl], 1);
            col[rpl[dl] + r] = (int)(p & 0xffffu);
        }
    }
}

// Fallback CSR fill for N > 65536 (not used at this problem size)
__launch_bounds__(256)
__global__ void fill_kernel(const int* __restrict__ src, const int* __restrict__ dst,
                            const int* __restrict__ rp, int* __restrict__ fill,
                            int* __restrict__ col, int e) {
    int i = blockIdx.x * 256 + threadIdx.x;
    if (i < e) {
        int d = dst[i];
        int pos = rp[d] + atomicAdd(&fill[d], 1);
        col[pos] = src[i];
    }
}

// ---------------- prep ----------------

// xs0[r] = dinv[r] * x[r], bf16 (row-prescaled input for the conv1 aggregate)
__launch_bounds__(256)
__global__ void cast_x_scaled(const float* __restrict__ x, const float* __restrict__ dinv,
                              bf16* __restrict__ out, int n64) {
    int i = blockIdx.x * 256 + threadIdx.x;
    if (i < n64) out[i] = (bf16)(x[i] * dinv[i >> 6]);
}

// fused: transpose+cast W1 (64x128), W2, W3 (128x128), cast lW1 (384x384)
__launch_bounds__(256)
__global__ void weight_prep(const float* __restrict__ W1, const float* __restrict__ W2,
                            const float* __restrict__ W3, const float* __restrict__ lW1,
                            bf16* __restrict__ Wt1, bf16* __restrict__ Wt2,
                            bf16* __restrict__ Wt3, bf16* __restrict__ lW1_bf) {
    int i = blockIdx.x * 256 + threadIdx.x;
    if (i < 8192) {
        int k = i >> 7, c = i & 127; Wt1[c * 64 + k] = (bf16)W1[i];
    } else if (i < 24576) {
        int j = i - 8192; int k = j >> 7, c = j & 127; Wt2[c * 128 + k] = (bf16)W2[j];
    } else if (i < 40960) {
        int j = i - 24576; int k = j >> 7, c = j & 127; Wt3[c * 128 + k] = (bf16)W3[j];
    } else if (i < 188416) {
        int j = i - 40960; lW1_bf[j] = (bf16)lW1[j];
    }
}

// ---------------- MFMA GEMM ----------------
// C[n x NO] = A[n x K, strideA] @ Bt[NO x K]^T. Tile 128x128, BK=32, 4 waves
// (2x2, each 64x64 = 4x4 frags of 16x16x32). Staging: global_load_lds x16,
// LDS 128 rows x 4 chunks of 16 B, chunk swizzle c^(r&3).
// EPI: 0 = rowScale only, 1 = +bias, 2 = +bias+ReLU.
template<int EPI>
__launch_bounds__(256, 4)
__global__ void mfma_gemm(const bf16* __restrict__ A, int strideA, int K,
                          const bf16* __restrict__ Bt,
                          const float* __restrict__ bias,
                          const float* __restrict__ rowScale,
                          bf16* __restrict__ C, int strideC, int n) {
    __shared__ bf16 As[128 * 32];
    __shared__ bf16 Bs[128 * 32];
    int t = threadIdx.x;
    int rowBase = blockIdx.x * 128;
    int colBase = blockIdx.y * 128;

    int lane = t & 63;
    int wv   = t >> 6;
    int wr   = wv >> 1, wc = wv & 1;
    int ml   = lane & 15, quad = lane >> 4;

    f32x4 acc[4][4];
#pragma unroll
    for (int i = 0; i < 4; ++i)
#pragma unroll
        for (int j = 0; j < 4; ++j) acc[i][j] = (f32x4){0.f, 0.f, 0.f, 0.f};

    int srow0 = wv * 32 + (lane >> 2);
    int cchunk = lane & 3;

    for (int kt = 0; kt < K; kt += 32) {
        __syncthreads();
#pragma unroll
        for (int inst = 0; inst < 2; ++inst) {
            int r  = srow0 + inst * 16;
            int gc = (cchunk ^ (r & 3)) * 8;
            int gr = rowBase + r; if (gr >= n) gr = n - 1;
            load_lds16(A + (size_t)gr * strideA + kt + gc,
                       &As[(wv * 128 + inst * 64) * 8]);
            int br = colBase + r;
            load_lds16(Bt + (size_t)br * K + kt + gc,
                       &Bs[(wv * 128 + inst * 64) * 8]);
        }
        __syncthreads();
        bf16x8 af[4], bfv[4];
#pragma unroll
        for (int i = 0; i < 4; ++i) {
            int ra = wr * 64 + i * 16 + ml;
            int rb = wc * 64 + i * 16 + ml;
            af[i]  = *(const bf16x8*)&As[(ra * 4 + (quad ^ (ra & 3))) * 8];
            bfv[i] = *(const bf16x8*)&Bs[(rb * 4 + (quad ^ (rb & 3))) * 8];
        }
#pragma unroll
        for (int i = 0; i < 4; ++i)
#pragma unroll
            for (int j = 0; j < 4; ++j)
                acc[i][j] = __builtin_amdgcn_mfma_f32_16x16x32_bf16(
                    af[i], bfv[j], acc[i][j], 0, 0, 0);
    }

#pragma unroll
    for (int i = 0; i < 4; ++i) {
#pragma unroll
        for (int reg = 0; reg < 4; ++reg) {
            int gr = rowBase + wr * 64 + i * 16 + quad * 4 + reg;
            if (gr < n) {
                float sc = (EPI == 0 && rowScale) ? rowScale[gr] : 1.f;
#pragma unroll
                for (int j = 0; j < 4; ++j) {
                    int gc = colBase + wc * 64 + j * 16 + ml;
                    float v = acc[i][j][reg];
                    if (EPI >= 1) v += bias[gc];
                    if (EPI == 2) v = fmaxf(v, 0.f);
                    C[(size_t)gr * strideC + gc] = (bf16)(v * sc);
                }
            }
        }
    }
}

// ---------------- aggregation ----------------
// 64-dim rows (conv1 input): one wave/node, lane = 1 col. xs pre-scaled by dinv.
__launch_bounds__(256)
__global__ void aggregate64(const bf16* __restrict__ xs, const int* __restrict__ rp,
                            const int* __restrict__ col, const float* __restrict__ dinv,
                            bf16* __restrict__ out, int n) {
    int gid  = blockIdx.x * 256 + threadIdx.x;
    int v    = gid >> 6;
    int lane = gid & 63;
    if (v >= n) return;
    float di = dinv[v];
    int b = rp[v], e = rp[v + 1];
    const bf16* base = xs + lane;
    float ax = 0.f;
    int j = b;
    for (; j + 8 <= e; j += 8) {
        float a0 = (float)base[(size_t)col[j]     * 64];
        float a1 = (float)base[(size_t)col[j + 1] * 64];
        float a2 = (float)base[(size_t)col[j + 2] * 64];
        float a3 = (float)base[(size_t)col[j + 3] * 64];
        float a4 = (float)base[(size_t)col[j + 4] * 64];
        float a5 = (float)base[(size_t)col[j + 5] * 64];
        float a6 = (float)base[(size_t)col[j + 6] * 64];
        float a7 = (float)base[(size_t)col[j + 7] * 64];
        ax += ((a0 + a1) + (a2 + a3)) + ((a4 + a5) + (a6 + a7));
    }
    for (; j < e; ++j) ax += (float)base[(size_t)col[j] * 64];
    ax = di * (ax + (float)base[(size_t)v * 64]);
    out[(size_t)v * 64 + lane] = (bf16)ax;
}

// 128-dim rows: one wave/node, lane = 2 cols. xs pre-scaled by dinv[src].
__launch_bounds__(256)
__global__ void aggregate(const bf16* __restrict__ xs, const int* __restrict__ rp,
                          const int* __restrict__ col, const float* __restrict__ dinv,
                          const float* __restrict__ bias, bf16* __restrict__ out,
                          int outStride, int n) {
    int gid  = blockIdx.x * 256 + threadIdx.x;
    int v    = gid >> 6;
    int lane = gid & 63;
    if (v >= n) return;
    float di = dinv[v];
    int b = rp[v], e = rp[v + 1];
    const bf16* base = xs + lane * 2;
    float ax = 0.f, ay = 0.f;
    int j = b;
    for (; j + 8 <= e; j += 8) {
        bf16x2 m0 = *(const bf16x2*)(base + (size_t)col[j]     * 128);
        bf16x2 m1 = *(const bf16x2*)(base + (size_t)col[j + 1] * 128);
        bf16x2 m2 = *(const bf16x2*)(base + (size_t)col[j + 2] * 128);
        bf16x2 m3 = *(const bf16x2*)(base + (size_t)col[j + 3] * 128);
        bf16x2 m4 = *(const bf16x2*)(base + (size_t)col[j + 4] * 128);
        bf16x2 m5 = *(const bf16x2*)(base + (size_t)col[j + 5] * 128);
        bf16x2 m6 = *(const bf16x2*)(base + (size_t)col[j + 6] * 128);
        bf16x2 m7 = *(const bf16x2*)(base + (size_t)col[j + 7] * 128);
        ax += (((float)m0[0] + (float)m1[0]) + ((float)m2[0] + (float)m3[0]))
            + (((float)m4[0] + (float)m5[0]) + ((float)m6[0] + (float)m7[0]));
        ay += (((float)m0[1] + (float)m1[1]) + ((float)m2[1] + (float)m3[1]))
            + (((float)m4[1] + (float)m5[1]) + ((float)m6[1] + (float)m7[1]));
    }
    for (; j < e; ++j) {
        bf16x2 m = *(const bf16x2*)(base + (size_t)col[j] * 128);
        ax += (float)m[0]; ay += (float)m[1];
    }
    bf16x2 mv = *(const bf16x2*)(base + (size_t)v * 128);
    ax = di * (ax + (float)mv[0]);
    ay = di * (ay + (float)mv[1]);
    float2 bb = *(const float2*)(bias + lane * 2);
    bf16x2 o;
    o[0] = (bf16)(ax + bb.x);
    o[1] = (bf16)(ay + bb.y);
    *(bf16x2*)(out + (size_t)v * outStride + lane * 2) = o;
}

// ---------------- linear2 + softmax ----------------
__launch_bounds__(256)
__global__ void linear2_softmax(const bf16* __restrict__ hrel, const float* __restrict__ lW2,
                                const float* __restrict__ lb2, float* __restrict__ out, int n) {
    int gid  = blockIdx.x * 256 + threadIdx.x;
    int node = gid >> 6;
    int lane = gid & 63;
    if (node >= n) return;
    const bf16* h = hrel + (size_t)node * 384;
    float a0 = 0.f, a1 = 0.f;
#pragma unroll
    for (int j = 0; j < 6; ++j) {
        int k = lane + j * 64;
        float hv = (float)h[k];
        a0 += hv * lW2[k];
        a1 += hv * lW2[384 + k];
    }
#pragma unroll
    for (int off = 32; off > 0; off >>= 1) {
        a0 += __shfl_down(a0, off, 64);
        a1 += __shfl_down(a1, off, 64);
    }
    if (lane == 0) {
        float l0 = a0 + lb2[0], l1 = a1 + lb2[1];
        out[(size_t)node * 2 + 0] = l0;
        out[(size_t)node * 2 + 1] = l1;
        float m  = fmaxf(l0, l1);
        float e0 = expf(l0 - m), e1 = expf(l1 - m);
        float inv = 1.f / (e0 + e1);
        out[(size_t)(n + node) * 2 + 0] = e0 * inv;
        out[(size_t)(n + node) * 2 + 1] = e1 * inv;
    }
}

extern "C" void kernel_launch(void* const* d_in, const int* in_sizes, int n_in,
                              void* d_out, int out_size, void* d_ws, size_t ws_size,
                              hipStream_t stream) {
    const float* x   = (const float*)d_in[0];
    const int*   ei  = (const int*)d_in[1];
    const float* W1  = (const float*)d_in[2];
    const float* b1  = (const float*)d_in[3];
    const float* W2  = (const float*)d_in[4];
    const float* b2  = (const float*)d_in[5];
    const float* W3  = (const float*)d_in[6];
    const float* b3  = (const float*)d_in[7];
    const float* lW1 = (const float*)d_in[8];
    const float* lb1 = (const float*)d_in[9];
    const float* lW2 = (const float*)d_in[10];
    const float* lb2 = (const float*)d_in[11];
    float* out = (float*)d_out;

    int N = in_sizes[0] / 64;
    int E = in_sizes[1] / 2;
    const int* src = ei;
    const int* dst = ei + E;

    char* ws = (char*)d_ws;
    size_t off = 0;
    auto take = [&](size_t bytes) -> char* {
        char* p = ws + off;
        off += (bytes + 255) & ~(size_t)255;
        return p;
    };
    int nBlk  = (N + 255) / 256;
    int nbuck = nBlk;                       // buckets of 256 dst nodes
    int*   cnt    = (int*)take((size_t)N * 4);
    int*   fill   = (int*)take((size_t)N * 4);
    int*   rp     = (int*)take((size_t)(N + 1) * 4);
    float* dinv   = (float*)take((size_t)N * 4);
    int*   bsum   = (int*)take((size_t)nBlk * 4);
    int*   tail   = (int*)take((size_t)nbuck * 4);
    int*   col    = (int*)take((size_t)E * 4);
    unsigned int* pairs = (unsigned int*)take((size_t)E * 4);
    bf16*  xs0    = (bf16*)take((size_t)N * 64 * 2);
    bf16*  ax     = (bf16*)take((size_t)N * 64 * 2);
    bf16*  Wt1    = (bf16*)take((size_t)64 * 128 * 2);
    bf16*  Wt2    = (bf16*)take((size_t)128 * 128 * 2);
    bf16*  Wt3    = (bf16*)take((size_t)128 * 128 * 2);
    bf16*  lW1_bf = (bf16*)take((size_t)384 * 384 * 2);
    bf16*  xw     = (bf16*)take((size_t)N * 128 * 2);
    bf16*  hcat   = (bf16*)take((size_t)N * 384 * 2);
    bf16*  hrel   = (bf16*)take((size_t)N * 384 * 2);

    // CSR build
    init_kernel<<<nBlk, 256, 0, stream>>>(cnt, fill, N);
    hist_kernel<<<(E + 255) / 256, 256, 0, stream>>>(dst, cnt, E);
    block_reduce<<<nBlk, 256, 0, stream>>>(cnt, bsum, N);
    scan_bsums<<<1, 256, 0, stream>>>(bsum, nBlk);
    write_rp<<<nBlk, 256, 0, stream>>>(cnt, bsum, rp, dinv, N, E);
    if (nbuck <= 256 && N <= 65536) {
        tail_init<<<1, 256, 0, stream>>>(rp, tail, nbuck);
        bin_pairs<<<nbuck, 256, 0, stream>>>(src, dst, tail, pairs, E, nbuck);
        csr_fill<<<nbuck, 256, 0, stream>>>(pairs, rp, col, N);
    } else {
        fill_kernel<<<(E + 255) / 256, 256, 0, stream>>>(src, dst, rp, fill, col, E);
    }

    // prep
    cast_x_scaled<<<(N * 64 + 255) / 256, 256, 0, stream>>>(x, dinv, xs0, N * 64);
    weight_prep<<<736, 256, 0, stream>>>(W1, W2, W3, lW1, Wt1, Wt2, Wt3, lW1_bf);

    int gemmBlocks = (N + 127) / 128;
    int aggBlocks  = (N + 3) / 4;

    // conv1: aggregate first (64-dim), then GEMM with bias epilogue
    aggregate64<<<aggBlocks, 256, 0, stream>>>(xs0, rp, col, dinv, ax, N);
    mfma_gemm<1><<<dim3(gemmBlocks, 1), 256, 0, stream>>>(
        ax, 64, 64, Wt1, b1, nullptr, hcat + 0, 384, N);
    // conv2: GEMM (rows pre-scaled by dinv) then aggregate (+bias)
    mfma_gemm<0><<<dim3(gemmBlocks, 1), 256, 0, stream>>>(
        hcat + 0, 384, 128, Wt2, nullptr, dinv, xw, 128, N);
    aggregate<<<aggBlocks, 256, 0, stream>>>(xw, rp, col, dinv, b2, hcat + 128, 384, N);
    // conv3
    mfma_gemm<0><<<dim3(gemmBlocks, 1), 256, 0, stream>>>(
        hcat + 128, 384, 128, Wt3, nullptr, dinv, xw, 128, N);
    aggregate<<<aggBlocks, 256, 0, stream>>>(xw, rp, col, dinv, b3, hcat + 256, 384, N);

    // MLP head
    mfma_gemm<2><<<dim3(gemmBlocks, 3), 256, 0, stream>>>(
        hcat, 384, 384, lW1_bf, lb1, nullptr, hrel, 384, N);
    linear2_softmax<<<(N + 3) / 4, 256, 0, stream>>>(hrel, lW2, lb2, out, N);
}

// Round 6
// 328.780 us; speedup vs baseline: 2.5939x; 1.0747x over previous
//
#include <hip/hip_runtime.h>
#include <hip/hip_bf16.h>
#include <cmath>

// ---------------------------------------------------------------------------
// Round 6:
//   - aggregate/aggregate64: one coalesced col load per 64 edges + readlane
//     broadcast -> gather addresses are SGPR-based (saddr global_load), no
//     col->gather latency chain per 8-edge group.
//   - tail_init folded into write_rp; cast_x_scaled+weight_prep fused.
//   - (From R5) binned CSR build; conv1 aggregates before GEMM; bf16 MFMA
//     128x128/BK32 GEMMs with global_load_lds w16 + XOR-swizzled LDS.
// ---------------------------------------------------------------------------

typedef __bf16 bf16;
typedef __bf16 bf16x2 __attribute__((ext_vector_type(2)));
typedef __bf16 bf16x8 __attribute__((ext_vector_type(8)));
typedef float  f32x4  __attribute__((ext_vector_type(4)));

__device__ __forceinline__ void load_lds16(const bf16* g, bf16* l) {
    __builtin_amdgcn_global_load_lds(
        (const __attribute__((address_space(1))) void*)g,
        (__attribute__((address_space(3))) void*)l, 16, 0, 0);
}

// ---------------- CSR build ----------------

__launch_bounds__(256)
__global__ void init_kernel(int* __restrict__ cnt, int* __restrict__ fill, int n) {
    int i = blockIdx.x * 256 + threadIdx.x;
    if (i < n) { cnt[i] = 1; fill[i] = 0; }   // cnt starts at 1: self-loop
}

__launch_bounds__(256)
__global__ void hist_kernel(const int* __restrict__ dst, int* __restrict__ cnt, int e) {
    int i = blockIdx.x * 256 + threadIdx.x;
    if (i < e) atomicAdd(&cnt[dst[i]], 1);
}

__launch_bounds__(256)
__global__ void block_reduce(const int* __restrict__ cnt, int* __restrict__ bsum, int n) {
    __shared__ int s[256];
    int t = threadIdx.x;
    int i = blockIdx.x * 256 + t;
    int v = (i < n) ? cnt[i] - 1 : 0;
    s[t] = v;
    __syncthreads();
#pragma unroll
    for (int off = 128; off > 0; off >>= 1) {
        if (t < off) s[t] += s[t + off];
        __syncthreads();
    }
    if (t == 0) bsum[blockIdx.x] = s[0];
}

__launch_bounds__(256)
__global__ void scan_bsums(int* __restrict__ bsum, int nb) {
    __shared__ int s[256];
    int t = threadIdx.x;
    int v = (t < nb) ? bsum[t] : 0;
    s[t] = v;
    __syncthreads();
#pragma unroll
    for (int off = 1; off < 256; off <<= 1) {
        int tmp = (t >= off) ? s[t - off] : 0;
        __syncthreads();
        s[t] += tmp;
        __syncthreads();
    }
    if (t < nb) bsum[t] = s[t] - v;   // exclusive
}

// per-block scan + global offset -> rp, dinv; also tail[b] = rp[b*256]
__launch_bounds__(256)
__global__ void write_rp(const int* __restrict__ cnt, const int* __restrict__ bsum,
                         int* __restrict__ rp, float* __restrict__ dinv,
                         int* __restrict__ tail, int n, int etot) {
    __shared__ int s[256];
    int t = threadIdx.x;
    int i = blockIdx.x * 256 + t;
    int c = (i < n) ? cnt[i] : 1;
    int v = c - 1;
    s[t] = v;
    __syncthreads();
#pragma unroll
    for (int off = 1; off < 256; off <<= 1) {
        int tmp = (t >= off) ? s[t - off] : 0;
        __syncthreads();
        s[t] += tmp;
        __syncthreads();
    }
    if (i < n) {
        int rpv = bsum[blockIdx.x] + s[t] - v;
        rp[i]   = rpv;
        if (t == 0) tail[blockIdx.x] = rpv;   // bucket base (256-aligned)
        dinv[i] = rsqrtf((float)c);
        if (i == n - 1) rp[n] = etot;
    }
}

// Pass 1: bin edges by dst>>8 into per-bucket regions of `pairs`.
// Packed u32 = src | (dst&255)<<16 (requires N <= 65536).
__launch_bounds__(256)
__global__ void bin_pairs(const int* __restrict__ src, const int* __restrict__ dst,
                          int* __restrict__ tail, unsigned int* __restrict__ pairs,
                          int e, int nbuck) {
    __shared__ int hist[256], base[256], cur[256];
    int t = threadIdx.x;
    hist[t] = 0; cur[t] = 0;
    __syncthreads();
    int perBlock = (e + gridDim.x - 1) / gridDim.x;
    int lo = blockIdx.x * perBlock;
    int hi = lo + perBlock; if (hi > e) hi = e;
    for (int i = lo + t; i < hi; i += 256)
        atomicAdd(&hist[dst[i] >> 8], 1);
    __syncthreads();
    if (t < nbuck && hist[t] > 0) base[t] = atomicAdd(&tail[t], hist[t]);
    __syncthreads();
    for (int i = lo + t; i < hi; i += 256) {
        int d = dst[i];
        int b = d >> 8;
        int r = atomicAdd(&cur[b], 1);
        pairs[base[b] + r] = (unsigned)src[i] | ((unsigned)(d & 255) << 16);
    }
}

// Pass 2: one block per bucket; scatter into LDS window, write col coalesced.
#define FILL_CAP 6144
__launch_bounds__(256)
__global__ void csr_fill(const unsigned int* __restrict__ pairs, const int* __restrict__ rp,
                         int* __restrict__ col, int n) {
    __shared__ int rpl[257];
    __shared__ int fillc[256];
    __shared__ int win[FILL_CAP];
    int b = blockIdx.x;
    int t = threadIdx.x;
    int nodeBase = b << 8;
    int nhi = n - nodeBase; if (nhi > 256) nhi = 256;
    for (int i = t; i <= nhi; i += 256) rpl[i] = rp[nodeBase + i];
    fillc[t] = 0;
    __syncthreads();
    int lo = rpl[0], hi = rpl[nhi];
    int cnt = hi - lo;
    if (cnt <= FILL_CAP) {
        for (int i = t; i < cnt; i += 256) {
            unsigned p = pairs[lo + i];
            int dl = (int)(p >> 16);
            int r = atomicAdd(&fillc[dl], 1);
            win[rpl[dl] - lo + r] = (int)(p & 0xffffu);
        }
        __syncthreads();
        for (int i = t; i < cnt; i += 256) col[lo + i] = win[i];
    } else {   // overflow fallback (never taken for random graphs)
        for (int i = t; i < cnt; i += 256) {
            unsigned p = pairs[lo + i];
            int dl = (int)(p >> 16);
            int r = atomicAdd(&fillc[dl], 1);
            col[rpl[dl] + r] = (int)(p & 0xffffu);
        }
    }
}

// Fallback CSR fill for N > 65536 (not used at this problem size)
__launch_bounds__(256)
__global__ void fill_kernel(const int* __restrict__ src, const int* __restrict__ dst,
                            const int* __restrict__ rp, int* __restrict__ fill,
                            int* __restrict__ col, int e) {
    int i = blockIdx.x * 256 + threadIdx.x;
    if (i < e) {
        int d = dst[i];
        int pos = rp[d] + atomicAdd(&fill[d], 1);
        col[pos] = src[i];
    }
}

// ---------------- prep (fused) ----------------
// regions: [0,8192) Wt1, [8192,24576) Wt2, [24576,40960) Wt3,
// [40960,188416) lW1 cast, [188416, 188416+n64) xs0 = dinv-scaled x cast
__launch_bounds__(256)
__global__ void prep_all(const float* __restrict__ W1, const float* __restrict__ W2,
                         const float* __restrict__ W3, const float* __restrict__ lW1,
                         const float* __restrict__ x, const float* __restrict__ dinv,
                         bf16* __restrict__ Wt1, bf16* __restrict__ Wt2,
                         bf16* __restrict__ Wt3, bf16* __restrict__ lW1_bf,
                         bf16* __restrict__ xs0, int n64) {
    int i = blockIdx.x * 256 + threadIdx.x;
    if (i < 8192) {
        int k = i >> 7, c = i & 127; Wt1[c * 64 + k] = (bf16)W1[i];
    } else if (i < 24576) {
        int j = i - 8192; int k = j >> 7, c = j & 127; Wt2[c * 128 + k] = (bf16)W2[j];
    } else if (i < 40960) {
        int j = i - 24576; int k = j >> 7, c = j & 127; Wt3[c * 128 + k] = (bf16)W3[j];
    } else if (i < 188416) {
        int j = i - 40960; lW1_bf[j] = (bf16)lW1[j];
    } else {
        int j = i - 188416;
        if (j < n64) xs0[j] = (bf16)(x[j] * dinv[j >> 6]);
    }
}

// ---------------- MFMA GEMM ----------------
// C[n x NO] = A[n x K, strideA] @ Bt[NO x K]^T. Tile 128x128, BK=32, 4 waves
// (2x2, each 64x64 = 4x4 frags of 16x16x32). Staging: global_load_lds x16,
// LDS 128 rows x 4 chunks of 16 B, chunk swizzle c^(r&3).
// EPI: 0 = rowScale only, 1 = +bias, 2 = +bias+ReLU.
template<int EPI>
__launch_bounds__(256, 4)
__global__ void mfma_gemm(const bf16* __restrict__ A, int strideA, int K,
                          const bf16* __restrict__ Bt,
                          const float* __restrict__ bias,
                          const float* __restrict__ rowScale,
                          bf16* __restrict__ C, int strideC, int n) {
    __shared__ bf16 As[128 * 32];
    __shared__ bf16 Bs[128 * 32];
    int t = threadIdx.x;
    int rowBase = blockIdx.x * 128;
    int colBase = blockIdx.y * 128;

    int lane = t & 63;
    int wv   = t >> 6;
    int wr   = wv >> 1, wc = wv & 1;
    int ml   = lane & 15, quad = lane >> 4;

    f32x4 acc[4][4];
#pragma unroll
    for (int i = 0; i < 4; ++i)
#pragma unroll
        for (int j = 0; j < 4; ++j) acc[i][j] = (f32x4){0.f, 0.f, 0.f, 0.f};

    int srow0 = wv * 32 + (lane >> 2);
    int cchunk = lane & 3;

    for (int kt = 0; kt < K; kt += 32) {
        __syncthreads();
#pragma unroll
        for (int inst = 0; inst < 2; ++inst) {
            int r  = srow0 + inst * 16;
            int gc = (cchunk ^ (r & 3)) * 8;
            int gr = rowBase + r; if (gr >= n) gr = n - 1;
            load_lds16(A + (size_t)gr * strideA + kt + gc,
                       &As[(wv * 128 + inst * 64) * 8]);
            int br = colBase + r;
            load_lds16(Bt + (size_t)br * K + kt + gc,
                       &Bs[(wv * 128 + inst * 64) * 8]);
        }
        __syncthreads();
        bf16x8 af[4], bfv[4];
#pragma unroll
        for (int i = 0; i < 4; ++i) {
            int ra = wr * 64 + i * 16 + ml;
            int rb = wc * 64 + i * 16 + ml;
            af[i]  = *(const bf16x8*)&As[(ra * 4 + (quad ^ (ra & 3))) * 8];
            bfv[i] = *(const bf16x8*)&Bs[(rb * 4 + (quad ^ (rb & 3))) * 8];
        }
#pragma unroll
        for (int i = 0; i < 4; ++i)
#pragma unroll
            for (int j = 0; j < 4; ++j)
                acc[i][j] = __builtin_amdgcn_mfma_f32_16x16x32_bf16(
                    af[i], bfv[j], acc[i][j], 0, 0, 0);
    }

#pragma unroll
    for (int i = 0; i < 4; ++i) {
#pragma unroll
        for (int reg = 0; reg < 4; ++reg) {
            int gr = rowBase + wr * 64 + i * 16 + quad * 4 + reg;
            if (gr < n) {
                float sc = (EPI == 0 && rowScale) ? rowScale[gr] : 1.f;
#pragma unroll
                for (int j = 0; j < 4; ++j) {
                    int gc = colBase + wc * 64 + j * 16 + ml;
                    float v = acc[i][j][reg];
                    if (EPI >= 1) v += bias[gc];
                    if (EPI == 2) v = fmaxf(v, 0.f);
                    C[(size_t)gr * strideC + gc] = (bf16)(v * sc);
                }
            }
        }
    }
}

// ---------------- aggregation ----------------
// col-broadcast pattern: one coalesced col load per 64 edges (lane i holds
// col[b+j0+i]); readlane -> SGPR gather base; 8 row-gathers in flight.

// 64-dim rows (conv1 input): one wave/node, lane = 1 col. xs pre-scaled.
__launch_bounds__(256)
__global__ void aggregate64(const bf16* __restrict__ xs, const int* __restrict__ rp,
                            const int* __restrict__ col, const float* __restrict__ dinv,
                            bf16* __restrict__ out, int n) {
    int gid  = blockIdx.x * 256 + threadIdx.x;
    int v    = gid >> 6;
    int lane = gid & 63;
    if (v >= n) return;
    float di = dinv[v];
    int b = rp[v], e = rp[v + 1];
    int deg = e - b;
    const bf16* base = xs + lane;
    float ax = 0.f;
    for (int j0 = 0; j0 < deg; j0 += 64) {
        int rem = deg - j0; if (rem > 64) rem = 64;
        int cj = (lane < rem) ? col[b + j0 + lane] : 0;
        int jj = 0;
        for (; jj + 8 <= rem; jj += 8) {
            int s0 = __builtin_amdgcn_readlane(cj, jj + 0);
            int s1 = __builtin_amdgcn_readlane(cj, jj + 1);
            int s2 = __builtin_amdgcn_readlane(cj, jj + 2);
            int s3 = __builtin_amdgcn_readlane(cj, jj + 3);
            int s4 = __builtin_amdgcn_readlane(cj, jj + 4);
            int s5 = __builtin_amdgcn_readlane(cj, jj + 5);
            int s6 = __builtin_amdgcn_readlane(cj, jj + 6);
            int s7 = __builtin_amdgcn_readlane(cj, jj + 7);
            float a0 = (float)base[(size_t)s0 * 64];
            float a1 = (float)base[(size_t)s1 * 64];
            float a2 = (float)base[(size_t)s2 * 64];
            float a3 = (float)base[(size_t)s3 * 64];
            float a4 = (float)base[(size_t)s4 * 64];
            float a5 = (float)base[(size_t)s5 * 64];
            float a6 = (float)base[(size_t)s6 * 64];
            float a7 = (float)base[(size_t)s7 * 64];
            ax += ((a0 + a1) + (a2 + a3)) + ((a4 + a5) + (a6 + a7));
        }
        for (; jj < rem; ++jj) {
            int s = __builtin_amdgcn_readlane(cj, jj);
            ax += (float)base[(size_t)s * 64];
        }
    }
    ax = di * (ax + (float)base[(size_t)v * 64]);
    out[(size_t)v * 64 + lane] = (bf16)ax;
}

// 128-dim rows: one wave/node, lane = 2 cols. xs pre-scaled by dinv[src].
__launch_bounds__(256)
__global__ void aggregate(const bf16* __restrict__ xs, const int* __restrict__ rp,
                          const int* __restrict__ col, const float* __restrict__ dinv,
                          const float* __restrict__ bias, bf16* __restrict__ out,
                          int outStride, int n) {
    int gid  = blockIdx.x * 256 + threadIdx.x;
    int v    = gid >> 6;
    int lane = gid & 63;
    if (v >= n) return;
    float di = dinv[v];
    int b = rp[v], e = rp[v + 1];
    int deg = e - b;
    const bf16* base = xs + lane * 2;
    float ax = 0.f, ay = 0.f;
    for (int j0 = 0; j0 < deg; j0 += 64) {
        int rem = deg - j0; if (rem > 64) rem = 64;
        int cj = (lane < rem) ? col[b + j0 + lane] : 0;
        int jj = 0;
        for (; jj + 8 <= rem; jj += 8) {
            int s0 = __builtin_amdgcn_readlane(cj, jj + 0);
            int s1 = __builtin_amdgcn_readlane(cj, jj + 1);
            int s2 = __builtin_amdgcn_readlane(cj, jj + 2);
            int s3 = __builtin_amdgcn_readlane(cj, jj + 3);
            int s4 = __builtin_amdgcn_readlane(cj, jj + 4);
            int s5 = __builtin_amdgcn_readlane(cj, jj + 5);
            int s6 = __builtin_amdgcn_readlane(cj, jj + 6);
            int s7 = __builtin_amdgcn_readlane(cj, jj + 7);
            bf16x2 m0 = *(const bf16x2*)(base + (size_t)s0 * 128);
            bf16x2 m1 = *(const bf16x2*)(base + (size_t)s1 * 128);
            bf16x2 m2 = *(const bf16x2*)(base + (size_t)s2 * 128);
            bf16x2 m3 = *(const bf16x2*)(base + (size_t)s3 * 128);
            bf16x2 m4 = *(const bf16x2*)(base + (size_t)s4 * 128);
            bf16x2 m5 = *(const bf16x2*)(base + (size_t)s5 * 128);
            bf16x2 m6 = *(const bf16x2*)(base + (size_t)s6 * 128);
            bf16x2 m7 = *(const bf16x2*)(base + (size_t)s7 * 128);
            ax += (((float)m0[0] + (float)m1[0]) + ((float)m2[0] + (float)m3[0]))
                + (((float)m4[0] + (float)m5[0]) + ((float)m6[0] + (float)m7[0]));
            ay += (((float)m0[1] + (float)m1[1]) + ((float)m2[1] + (float)m3[1]))
                + (((float)m4[1] + (float)m5[1]) + ((float)m6[1] + (float)m7[1]));
        }
        for (; jj < rem; ++jj) {
            int s = __builtin_amdgcn_readlane(cj, jj);
            bf16x2 m = *(const bf16x2*)(base + (size_t)s * 128);
            ax += (float)m[0]; ay += (float)m[1];
        }
    }
    bf16x2 mv = *(const bf16x2*)(base + (size_t)v * 128);
    ax = di * (ax + (float)mv[0]);
    ay = di * (ay + (float)mv[1]);
    float2 bb = *(const float2*)(bias + lane * 2);
    bf16x2 o;
    o[0] = (bf16)(ax + bb.x);
    o[1] = (bf16)(ay + bb.y);
    *(bf16x2*)(out + (size_t)v * outStride + lane * 2) = o;
}

// ---------------- linear2 + softmax ----------------
__launch_bounds__(256)
__global__ void linear2_softmax(const bf16* __restrict__ hrel, const float* __restrict__ lW2,
                                const float* __restrict__ lb2, float* __restrict__ out, int n) {
    int gid  = blockIdx.x * 256 + threadIdx.x;
    int node = gid >> 6;
    int lane = gid & 63;
    if (node >= n) return;
    const bf16* h = hrel + (size_t)node * 384;
    float a0 = 0.f, a1 = 0.f;
#pragma unroll
    for (int j = 0; j < 6; ++j) {
        int k = lane + j * 64;
        float hv = (float)h[k];
        a0 += hv * lW2[k];
        a1 += hv * lW2[384 + k];
    }
#pragma unroll
    for (int off = 32; off > 0; off >>= 1) {
        a0 += __shfl_down(a0, off, 64);
        a1 += __shfl_down(a1, off, 64);
    }
    if (lane == 0) {
        float l0 = a0 + lb2[0], l1 = a1 + lb2[1];
        out[(size_t)node * 2 + 0] = l0;
        out[(size_t)node * 2 + 1] = l1;
        float m  = fmaxf(l0, l1);
        float e0 = expf(l0 - m), e1 = expf(l1 - m);
        float inv = 1.f / (e0 + e1);
        out[(size_t)(n + node) * 2 + 0] = e0 * inv;
        out[(size_t)(n + node) * 2 + 1] = e1 * inv;
    }
}

extern "C" void kernel_launch(void* const* d_in, const int* in_sizes, int n_in,
                              void* d_out, int out_size, void* d_ws, size_t ws_size,
                              hipStream_t stream) {
    const float* x   = (const float*)d_in[0];
    const int*   ei  = (const int*)d_in[1];
    const float* W1  = (const float*)d_in[2];
    const float* b1  = (const float*)d_in[3];
    const float* W2  = (const float*)d_in[4];
    const float* b2  = (const float*)d_in[5];
    const float* W3  = (const float*)d_in[6];
    const float* b3  = (const float*)d_in[7];
    const float* lW1 = (const float*)d_in[8];
    const float* lb1 = (const float*)d_in[9];
    const float* lW2 = (const float*)d_in[10];
    const float* lb2 = (const float*)d_in[11];
    float* out = (float*)d_out;

    int N = in_sizes[0] / 64;
    int E = in_sizes[1] / 2;
    const int* src = ei;
    const int* dst = ei + E;

    char* ws = (char*)d_ws;
    size_t off = 0;
    auto take = [&](size_t bytes) -> char* {
        char* p = ws + off;
        off += (bytes + 255) & ~(size_t)255;
        return p;
    };
    int nBlk  = (N + 255) / 256;
    int nbuck = nBlk;                       // buckets of 256 dst nodes
    int*   cnt    = (int*)take((size_t)N * 4);
    int*   fill   = (int*)take((size_t)N * 4);
    int*   rp     = (int*)take((size_t)(N + 1) * 4);
    float* dinv   = (float*)take((size_t)N * 4);
    int*   bsum   = (int*)take((size_t)nBlk * 4);
    int*   tail   = (int*)take((size_t)nbuck * 4);
    int*   col    = (int*)take((size_t)E * 4);
    unsigned int* pairs = (unsigned int*)take((size_t)E * 4);
    bf16*  xs0    = (bf16*)take((size_t)N * 64 * 2);
    bf16*  ax     = (bf16*)take((size_t)N * 64 * 2);
    bf16*  Wt1    = (bf16*)take((size_t)64 * 128 * 2);
    bf16*  Wt2    = (bf16*)take((size_t)128 * 128 * 2);
    bf16*  Wt3    = (bf16*)take((size_t)128 * 128 * 2);
    bf16*  lW1_bf = (bf16*)take((size_t)384 * 384 * 2);
    bf16*  xw     = (bf16*)take((size_t)N * 128 * 2);
    bf16*  hcat   = (bf16*)take((size_t)N * 384 * 2);
    bf16*  hrel   = (bf16*)take((size_t)N * 384 * 2);

    // CSR build
    init_kernel<<<nBlk, 256, 0, stream>>>(cnt, fill, N);
    hist_kernel<<<(E + 255) / 256, 256, 0, stream>>>(dst, cnt, E);
    block_reduce<<<nBlk, 256, 0, stream>>>(cnt, bsum, N);
    scan_bsums<<<1, 256, 0, stream>>>(bsum, nBlk);
    write_rp<<<nBlk, 256, 0, stream>>>(cnt, bsum, rp, dinv, tail, N, E);
    if (nbuck <= 256 && N <= 65536) {
        bin_pairs<<<nbuck, 256, 0, stream>>>(src, dst, tail, pairs, E, nbuck);
        csr_fill<<<nbuck, 256, 0, stream>>>(pairs, rp, col, N);
    } else {
        fill_kernel<<<(E + 255) / 256, 256, 0, stream>>>(src, dst, rp, fill, col, E);
    }

    // prep (weights + dinv-scaled x cast, one launch)
    int prepElems = 188416 + N * 64;
    prep_all<<<(prepElems + 255) / 256, 256, 0, stream>>>(
        W1, W2, W3, lW1, x, dinv, Wt1, Wt2, Wt3, lW1_bf, xs0, N * 64);

    int gemmBlocks = (N + 127) / 128;
    int aggBlocks  = (N + 3) / 4;

    // conv1: aggregate first (64-dim), then GEMM with bias epilogue
    aggregate64<<<aggBlocks, 256, 0, stream>>>(xs0, rp, col, dinv, ax, N);
    mfma_gemm<1><<<dim3(gemmBlocks, 1), 256, 0, stream>>>(
        ax, 64, 64, Wt1, b1, nullptr, hcat + 0, 384, N);
    // conv2: GEMM (rows pre-scaled by dinv) then aggregate (+bias)
    mfma_gemm<0><<<dim3(gemmBlocks, 1), 256, 0, stream>>>(
        hcat + 0, 384, 128, Wt2, nullptr, dinv, xw, 128, N);
    aggregate<<<aggBlocks, 256, 0, stream>>>(xw, rp, col, dinv, b2, hcat + 128, 384, N);
    // conv3
    mfma_gemm<0><<<dim3(gemmBlocks, 1), 256, 0, stream>>>(
        hcat + 128, 384, 128, Wt3, nullptr, dinv, xw, 128, N);
    aggregate<<<aggBlocks, 256, 0, stream>>>(xw, rp, col, dinv, b3, hcat + 256, 384, N);

    // MLP head
    mfma_gemm<2><<<dim3(gemmBlocks, 3), 256, 0, stream>>>(
        hcat, 384, 384, lW1_bf, lb1, nullptr, hrel, 384, N);
    linear2_softmax<<<(N + 3) / 4, 256, 0, stream>>>(hrel, lW2, lb2, out, N);
}

// Round 7
// 318.282 us; speedup vs baseline: 2.6794x; 1.0330x over previous
//
#include <hip/hip_runtime.h>
#include <hip/hip_bf16.h>
#include <hip/hip_fp8.h>
#include <cmath>

// ---------------------------------------------------------------------------
// Round 7:
//   - conv2/conv3 intermediate xw stored as fp8 e4m3 (OCP): halves the two
//     big 128-dim gather streams (218 -> 109 MB each) and the GEMM epilogue
//     writes; xw drops to 6.4 MB (~L2-resident). conv1 path stays bf16 for
//     error headroom. GEMM accumulation stays fp32; hcat/hrel stay bf16.
//   - (R6) readlane-broadcast aggregates; (R5) binned CSR build; bf16 MFMA
//     128x128/BK32 GEMMs with global_load_lds w16 + XOR-swizzled LDS.
// ---------------------------------------------------------------------------

typedef __bf16 bf16;
typedef __bf16 bf16x2 __attribute__((ext_vector_type(2)));
typedef __bf16 bf16x8 __attribute__((ext_vector_type(8)));
typedef float  f32x4  __attribute__((ext_vector_type(4)));
typedef unsigned char fp8s;   // e4m3 storage byte

__device__ __forceinline__ void load_lds16(const bf16* g, bf16* l) {
    __builtin_amdgcn_global_load_lds(
        (const __attribute__((address_space(1))) void*)g,
        (__attribute__((address_space(3))) void*)l, 16, 0, 0);
}

__device__ __forceinline__ bf16 convert_out(float v, bf16*) { return (bf16)v; }
__device__ __forceinline__ fp8s convert_out(float v, fp8s*) {
    __hip_fp8_e4m3 q(v); return (fp8s)q.__x;
}

// ---------------- CSR build ----------------

__launch_bounds__(256)
__global__ void init_kernel(int* __restrict__ cnt, int* __restrict__ fill, int n) {
    int i = blockIdx.x * 256 + threadIdx.x;
    if (i < n) { cnt[i] = 1; fill[i] = 0; }   // cnt starts at 1: self-loop
}

__launch_bounds__(256)
__global__ void hist_kernel(const int* __restrict__ dst, int* __restrict__ cnt, int e) {
    int i = blockIdx.x * 256 + threadIdx.x;
    if (i < e) atomicAdd(&cnt[dst[i]], 1);
}

__launch_bounds__(256)
__global__ void block_reduce(const int* __restrict__ cnt, int* __restrict__ bsum, int n) {
    __shared__ int s[256];
    int t = threadIdx.x;
    int i = blockIdx.x * 256 + t;
    int v = (i < n) ? cnt[i] - 1 : 0;
    s[t] = v;
    __syncthreads();
#pragma unroll
    for (int off = 128; off > 0; off >>= 1) {
        if (t < off) s[t] += s[t + off];
        __syncthreads();
    }
    if (t == 0) bsum[blockIdx.x] = s[0];
}

__launch_bounds__(256)
__global__ void scan_bsums(int* __restrict__ bsum, int nb) {
    __shared__ int s[256];
    int t = threadIdx.x;
    int v = (t < nb) ? bsum[t] : 0;
    s[t] = v;
    __syncthreads();
#pragma unroll
    for (int off = 1; off < 256; off <<= 1) {
        int tmp = (t >= off) ? s[t - off] : 0;
        __syncthreads();
        s[t] += tmp;
        __syncthreads();
    }
    if (t < nb) bsum[t] = s[t] - v;   // exclusive
}

// per-block scan + global offset -> rp, dinv; also tail[b] = rp[b*256]
__launch_bounds__(256)
__global__ void write_rp(const int* __restrict__ cnt, const int* __restrict__ bsum,
                         int* __restrict__ rp, float* __restrict__ dinv,
                         int* __restrict__ tail, int n, int etot) {
    __shared__ int s[256];
    int t = threadIdx.x;
    int i = blockIdx.x * 256 + t;
    int c = (i < n) ? cnt[i] : 1;
    int v = c - 1;
    s[t] = v;
    __syncthreads();
#pragma unroll
    for (int off = 1; off < 256; off <<= 1) {
        int tmp = (t >= off) ? s[t - off] : 0;
        __syncthreads();
        s[t] += tmp;
        __syncthreads();
    }
    if (i < n) {
        int rpv = bsum[blockIdx.x] + s[t] - v;
        rp[i]   = rpv;
        if (t == 0) tail[blockIdx.x] = rpv;   // bucket base (256-aligned)
        dinv[i] = rsqrtf((float)c);
        if (i == n - 1) rp[n] = etot;
    }
}

// Pass 1: bin edges by dst>>8 into per-bucket regions of `pairs`.
// Packed u32 = src | (dst&255)<<16 (requires N <= 65536).
__launch_bounds__(256)
__global__ void bin_pairs(const int* __restrict__ src, const int* __restrict__ dst,
                          int* __restrict__ tail, unsigned int* __restrict__ pairs,
                          int e, int nbuck) {
    __shared__ int hist[256], base[256], cur[256];
    int t = threadIdx.x;
    hist[t] = 0; cur[t] = 0;
    __syncthreads();
    int perBlock = (e + gridDim.x - 1) / gridDim.x;
    int lo = blockIdx.x * perBlock;
    int hi = lo + perBlock; if (hi > e) hi = e;
    for (int i = lo + t; i < hi; i += 256)
        atomicAdd(&hist[dst[i] >> 8], 1);
    __syncthreads();
    if (t < nbuck && hist[t] > 0) base[t] = atomicAdd(&tail[t], hist[t]);
    __syncthreads();
    for (int i = lo + t; i < hi; i += 256) {
        int d = dst[i];
        int b = d >> 8;
        int r = atomicAdd(&cur[b], 1);
        pairs[base[b] + r] = (unsigned)src[i] | ((unsigned)(d & 255) << 16);
    }
}

// Pass 2: one block per bucket; scatter into LDS window, write col coalesced.
#define FILL_CAP 6144
__launch_bounds__(256)
__global__ void csr_fill(const unsigned int* __restrict__ pairs, const int* __restrict__ rp,
                         int* __restrict__ col, int n) {
    __shared__ int rpl[257];
    __shared__ int fillc[256];
    __shared__ int win[FILL_CAP];
    int b = blockIdx.x;
    int t = threadIdx.x;
    int nodeBase = b << 8;
    int nhi = n - nodeBase; if (nhi > 256) nhi = 256;
    for (int i = t; i <= nhi; i += 256) rpl[i] = rp[nodeBase + i];
    fillc[t] = 0;
    __syncthreads();
    int lo = rpl[0], hi = rpl[nhi];
    int cnt = hi - lo;
    if (cnt <= FILL_CAP) {
        for (int i = t; i < cnt; i += 256) {
            unsigned p = pairs[lo + i];
            int dl = (int)(p >> 16);
            int r = atomicAdd(&fillc[dl], 1);
            win[rpl[dl] - lo + r] = (int)(p & 0xffffu);
        }
        __syncthreads();
        for (int i = t; i < cnt; i += 256) col[lo + i] = win[i];
    } else {   // overflow fallback (never taken for random graphs)
        for (int i = t; i < cnt; i += 256) {
            unsigned p = pairs[lo + i];
            int dl = (int)(p >> 16);
            int r = atomicAdd(&fillc[dl], 1);
            col[rpl[dl] + r] = (int)(p & 0xffffu);
        }
    }
}

// Fallback CSR fill for N > 65536 (not used at this problem size)
__launch_bounds__(256)
__global__ void fill_kernel(const int* __restrict__ src, const int* __restrict__ dst,
                            const int* __restrict__ rp, int* __restrict__ fill,
                            int* __restrict__ col, int e) {
    int i = blockIdx.x * 256 + threadIdx.x;
    if (i < e) {
        int d = dst[i];
        int pos = rp[d] + atomicAdd(&fill[d], 1);
        col[pos] = src[i];
    }
}

// ---------------- prep (fused) ----------------
// regions: [0,8192) Wt1, [8192,24576) Wt2, [24576,40960) Wt3,
// [40960,188416) lW1 cast, [188416, 188416+n64) xs0 = dinv-scaled x cast
__launch_bounds__(256)
__global__ void prep_all(const float* __restrict__ W1, const float* __restrict__ W2,
                         const float* __restrict__ W3, const float* __restrict__ lW1,
                         const float* __restrict__ x, const float* __restrict__ dinv,
                         bf16* __restrict__ Wt1, bf16* __restrict__ Wt2,
                         bf16* __restrict__ Wt3, bf16* __restrict__ lW1_bf,
                         bf16* __restrict__ xs0, int n64) {
    int i = blockIdx.x * 256 + threadIdx.x;
    if (i < 8192) {
        int k = i >> 7, c = i & 127; Wt1[c * 64 + k] = (bf16)W1[i];
    } else if (i < 24576) {
        int j = i - 8192; int k = j >> 7, c = j & 127; Wt2[c * 128 + k] = (bf16)W2[j];
    } else if (i < 40960) {
        int j = i - 24576; int k = j >> 7, c = j & 127; Wt3[c * 128 + k] = (bf16)W3[j];
    } else if (i < 188416) {
        int j = i - 40960; lW1_bf[j] = (bf16)lW1[j];
    } else {
        int j = i - 188416;
        if (j < n64) xs0[j] = (bf16)(x[j] * dinv[j >> 6]);
    }
}

// ---------------- MFMA GEMM ----------------
// C[n x NO] = A[n x K, strideA] @ Bt[NO x K]^T. Tile 128x128, BK=32, 4 waves
// (2x2, each 64x64 = 4x4 frags of 16x16x32). Staging: global_load_lds x16,
// LDS 128 rows x 4 chunks of 16 B, chunk swizzle c^(r&3).
// EPI: 0 = rowScale only, 1 = +bias, 2 = +bias+ReLU. OutT: bf16 or fp8s.
template<int EPI, typename OutT>
__launch_bounds__(256, 4)
__global__ void mfma_gemm(const bf16* __restrict__ A, int strideA, int K,
                          const bf16* __restrict__ Bt,
                          const float* __restrict__ bias,
                          const float* __restrict__ rowScale,
                          OutT* __restrict__ C, int strideC, int n) {
    __shared__ bf16 As[128 * 32];
    __shared__ bf16 Bs[128 * 32];
    int t = threadIdx.x;
    int rowBase = blockIdx.x * 128;
    int colBase = blockIdx.y * 128;

    int lane = t & 63;
    int wv   = t >> 6;
    int wr   = wv >> 1, wc = wv & 1;
    int ml   = lane & 15, quad = lane >> 4;

    f32x4 acc[4][4];
#pragma unroll
    for (int i = 0; i < 4; ++i)
#pragma unroll
        for (int j = 0; j < 4; ++j) acc[i][j] = (f32x4){0.f, 0.f, 0.f, 0.f};

    int srow0 = wv * 32 + (lane >> 2);
    int cchunk = lane & 3;

    for (int kt = 0; kt < K; kt += 32) {
        __syncthreads();
#pragma unroll
        for (int inst = 0; inst < 2; ++inst) {
            int r  = srow0 + inst * 16;
            int gc = (cchunk ^ (r & 3)) * 8;
            int gr = rowBase + r; if (gr >= n) gr = n - 1;
            load_lds16(A + (size_t)gr * strideA + kt + gc,
                       &As[(wv * 128 + inst * 64) * 8]);
            int br = colBase + r;
            load_lds16(Bt + (size_t)br * K + kt + gc,
                       &Bs[(wv * 128 + inst * 64) * 8]);
        }
        __syncthreads();
        bf16x8 af[4], bfv[4];
#pragma unroll
        for (int i = 0; i < 4; ++i) {
            int ra = wr * 64 + i * 16 + ml;
            int rb = wc * 64 + i * 16 + ml;
            af[i]  = *(const bf16x8*)&As[(ra * 4 + (quad ^ (ra & 3))) * 8];
            bfv[i] = *(const bf16x8*)&Bs[(rb * 4 + (quad ^ (rb & 3))) * 8];
        }
#pragma unroll
        for (int i = 0; i < 4; ++i)
#pragma unroll
            for (int j = 0; j < 4; ++j)
                acc[i][j] = __builtin_amdgcn_mfma_f32_16x16x32_bf16(
                    af[i], bfv[j], acc[i][j], 0, 0, 0);
    }

#pragma unroll
    for (int i = 0; i < 4; ++i) {
#pragma unroll
        for (int reg = 0; reg < 4; ++reg) {
            int gr = rowBase + wr * 64 + i * 16 + quad * 4 + reg;
            if (gr < n) {
                float sc = (EPI == 0 && rowScale) ? rowScale[gr] : 1.f;
#pragma unroll
                for (int j = 0; j < 4; ++j) {
                    int gc = colBase + wc * 64 + j * 16 + ml;
                    float v = acc[i][j][reg];
                    if (EPI >= 1) v += bias[gc];
                    if (EPI == 2) v = fmaxf(v, 0.f);
                    C[(size_t)gr * strideC + gc] = convert_out(v * sc, (OutT*)nullptr);
                }
            }
        }
    }
}

// ---------------- aggregation ----------------
// col-broadcast pattern: one coalesced col load per 64 edges; readlane ->
// SGPR gather base; 8 row-gathers in flight.

// 64-dim bf16 rows (conv1 input): one wave/node, lane = 1 col.
__launch_bounds__(256)
__global__ void aggregate64(const bf16* __restrict__ xs, const int* __restrict__ rp,
                            const int* __restrict__ col, const float* __restrict__ dinv,
                            bf16* __restrict__ out, int n) {
    int gid  = blockIdx.x * 256 + threadIdx.x;
    int v    = gid >> 6;
    int lane = gid & 63;
    if (v >= n) return;
    float di = dinv[v];
    int b = rp[v], e = rp[v + 1];
    int deg = e - b;
    const bf16* base = xs + lane;
    float ax = 0.f;
    for (int j0 = 0; j0 < deg; j0 += 64) {
        int rem = deg - j0; if (rem > 64) rem = 64;
        int cj = (lane < rem) ? col[b + j0 + lane] : 0;
        int jj = 0;
        for (; jj + 8 <= rem; jj += 8) {
            int s0 = __builtin_amdgcn_readlane(cj, jj + 0);
            int s1 = __builtin_amdgcn_readlane(cj, jj + 1);
            int s2 = __builtin_amdgcn_readlane(cj, jj + 2);
            int s3 = __builtin_amdgcn_readlane(cj, jj + 3);
            int s4 = __builtin_amdgcn_readlane(cj, jj + 4);
            int s5 = __builtin_amdgcn_readlane(cj, jj + 5);
            int s6 = __builtin_amdgcn_readlane(cj, jj + 6);
            int s7 = __builtin_amdgcn_readlane(cj, jj + 7);
            float a0 = (float)base[(size_t)s0 * 64];
            float a1 = (float)base[(size_t)s1 * 64];
            float a2 = (float)base[(size_t)s2 * 64];
            float a3 = (float)base[(size_t)s3 * 64];
            float a4 = (float)base[(size_t)s4 * 64];
            float a5 = (float)base[(size_t)s5 * 64];
            float a6 = (float)base[(size_t)s6 * 64];
            float a7 = (float)base[(size_t)s7 * 64];
            ax += ((a0 + a1) + (a2 + a3)) + ((a4 + a5) + (a6 + a7));
        }
        for (; jj < rem; ++jj) {
            int s = __builtin_amdgcn_readlane(cj, jj);
            ax += (float)base[(size_t)s * 64];
        }
    }
    ax = di * (ax + (float)base[(size_t)v * 64]);
    out[(size_t)v * 64 + lane] = (bf16)ax;
}

// 128-dim fp8 rows: one wave/node, lane = 2 cols (2 B/lane = 128 B/edge).
__launch_bounds__(256)
__global__ void aggregate_fp8(const fp8s* __restrict__ xs, const int* __restrict__ rp,
                              const int* __restrict__ col, const float* __restrict__ dinv,
                              const float* __restrict__ bias, bf16* __restrict__ out,
                              int outStride, int n) {
    int gid  = blockIdx.x * 256 + threadIdx.x;
    int v    = gid >> 6;
    int lane = gid & 63;
    if (v >= n) return;
    float di = dinv[v];
    int b = rp[v], e = rp[v + 1];
    int deg = e - b;
    const fp8s* base = xs + lane * 2;
    float ax = 0.f, ay = 0.f;
    for (int j0 = 0; j0 < deg; j0 += 64) {
        int rem = deg - j0; if (rem > 64) rem = 64;
        int cj = (lane < rem) ? col[b + j0 + lane] : 0;
        int jj = 0;
        for (; jj + 8 <= rem; jj += 8) {
            int s0 = __builtin_amdgcn_readlane(cj, jj + 0);
            int s1 = __builtin_amdgcn_readlane(cj, jj + 1);
            int s2 = __builtin_amdgcn_readlane(cj, jj + 2);
            int s3 = __builtin_amdgcn_readlane(cj, jj + 3);
            int s4 = __builtin_amdgcn_readlane(cj, jj + 4);
            int s5 = __builtin_amdgcn_readlane(cj, jj + 5);
            int s6 = __builtin_amdgcn_readlane(cj, jj + 6);
            int s7 = __builtin_amdgcn_readlane(cj, jj + 7);
            __hip_fp8x2_e4m3 m0, m1, m2, m3, m4, m5, m6, m7;
            m0.__x = *(const __hip_fp8x2_storage_t*)(base + (size_t)s0 * 128);
            m1.__x = *(const __hip_fp8x2_storage_t*)(base + (size_t)s1 * 128);
            m2.__x = *(const __hip_fp8x2_storage_t*)(base + (size_t)s2 * 128);
            m3.__x = *(const __hip_fp8x2_storage_t*)(base + (size_t)s3 * 128);
            m4.__x = *(const __hip_fp8x2_storage_t*)(base + (size_t)s4 * 128);
            m5.__x = *(const __hip_fp8x2_storage_t*)(base + (size_t)s5 * 128);
            m6.__x = *(const __hip_fp8x2_storage_t*)(base + (size_t)s6 * 128);
            m7.__x = *(const __hip_fp8x2_storage_t*)(base + (size_t)s7 * 128);
            float2 f0 = (float2)m0, f1 = (float2)m1, f2 = (float2)m2, f3 = (float2)m3;
            float2 f4 = (float2)m4, f5 = (float2)m5, f6 = (float2)m6, f7 = (float2)m7;
            ax += ((f0.x + f1.x) + (f2.x + f3.x)) + ((f4.x + f5.x) + (f6.x + f7.x));
            ay += ((f0.y + f1.y) + (f2.y + f3.y)) + ((f4.y + f5.y) + (f6.y + f7.y));
        }
        for (; jj < rem; ++jj) {
            int s = __builtin_amdgcn_readlane(cj, jj);
            __hip_fp8x2_e4m3 m;
            m.__x = *(const __hip_fp8x2_storage_t*)(base + (size_t)s * 128);
            float2 f = (float2)m;
            ax += f.x; ay += f.y;
        }
    }
    __hip_fp8x2_e4m3 mv;
    mv.__x = *(const __hip_fp8x2_storage_t*)(base + (size_t)v * 128);
    float2 fv = (float2)mv;
    ax = di * (ax + fv.x);
    ay = di * (ay + fv.y);
    float2 bb = *(const float2*)(bias + lane * 2);
    bf16x2 o;
    o[0] = (bf16)(ax + bb.x);
    o[1] = (bf16)(ay + bb.y);
    *(bf16x2*)(out + (size_t)v * outStride + lane * 2) = o;
}

// ---------------- linear2 + softmax ----------------
__launch_bounds__(256)
__global__ void linear2_softmax(const bf16* __restrict__ hrel, const float* __restrict__ lW2,
                                const float* __restrict__ lb2, float* __restrict__ out, int n) {
    int gid  = blockIdx.x * 256 + threadIdx.x;
    int node = gid >> 6;
    int lane = gid & 63;
    if (node >= n) return;
    const bf16* h = hrel + (size_t)node * 384;
    float a0 = 0.f, a1 = 0.f;
#pragma unroll
    for (int j = 0; j < 6; ++j) {
        int k = lane + j * 64;
        float hv = (float)h[k];
        a0 += hv * lW2[k];
        a1 += hv * lW2[384 + k];
    }
#pragma unroll
    for (int off = 32; off > 0; off >>= 1) {
        a0 += __shfl_down(a0, off, 64);
        a1 += __shfl_down(a1, off, 64);
    }
    if (lane == 0) {
        float l0 = a0 + lb2[0], l1 = a1 + lb2[1];
        out[(size_t)node * 2 + 0] = l0;
        out[(size_t)node * 2 + 1] = l1;
        float m  = fmaxf(l0, l1);
        float e0 = expf(l0 - m), e1 = expf(l1 - m);
        float inv = 1.f / (e0 + e1);
        out[(size_t)(n + node) * 2 + 0] = e0 * inv;
        out[(size_t)(n + node) * 2 + 1] = e1 * inv;
    }
}

extern "C" void kernel_launch(void* const* d_in, const int* in_sizes, int n_in,
                              void* d_out, int out_size, void* d_ws, size_t ws_size,
                              hipStream_t stream) {
    const float* x   = (const float*)d_in[0];
    const int*   ei  = (const int*)d_in[1];
    const float* W1  = (const float*)d_in[2];
    const float* b1  = (const float*)d_in[3];
    const float* W2  = (const float*)d_in[4];
    const float* b2  = (const float*)d_in[5];
    const float* W3  = (const float*)d_in[6];
    const float* b3  = (const float*)d_in[7];
    const float* lW1 = (const float*)d_in[8];
    const float* lb1 = (const float*)d_in[9];
    const float* lW2 = (const float*)d_in[10];
    const float* lb2 = (const float*)d_in[11];
    float* out = (float*)d_out;

    int N = in_sizes[0] / 64;
    int E = in_sizes[1] / 2;
    const int* src = ei;
    const int* dst = ei + E;

    char* ws = (char*)d_ws;
    size_t off = 0;
    auto take = [&](size_t bytes) -> char* {
        char* p = ws + off;
        off += (bytes + 255) & ~(size_t)255;
        return p;
    };
    int nBlk  = (N + 255) / 256;
    int nbuck = nBlk;                       // buckets of 256 dst nodes
    int*   cnt    = (int*)take((size_t)N * 4);
    int*   fill   = (int*)take((size_t)N * 4);
    int*   rp     = (int*)take((size_t)(N + 1) * 4);
    float* dinv   = (float*)take((size_t)N * 4);
    int*   bsum   = (int*)take((size_t)nBlk * 4);
    int*   tail   = (int*)take((size_t)nbuck * 4);
    int*   col    = (int*)take((size_t)E * 4);
    unsigned int* pairs = (unsigned int*)take((size_t)E * 4);
    bf16*  xs0    = (bf16*)take((size_t)N * 64 * 2);
    bf16*  ax     = (bf16*)take((size_t)N * 64 * 2);
    bf16*  Wt1    = (bf16*)take((size_t)64 * 128 * 2);
    bf16*  Wt2    = (bf16*)take((size_t)128 * 128 * 2);
    bf16*  Wt3    = (bf16*)take((size_t)128 * 128 * 2);
    bf16*  lW1_bf = (bf16*)take((size_t)384 * 384 * 2);
    fp8s*  xw8    = (fp8s*)take((size_t)N * 128);
    bf16*  hcat   = (bf16*)take((size_t)N * 384 * 2);
    bf16*  hrel   = (bf16*)take((size_t)N * 384 * 2);

    // CSR build
    init_kernel<<<nBlk, 256, 0, stream>>>(cnt, fill, N);
    hist_kernel<<<(E + 255) / 256, 256, 0, stream>>>(dst, cnt, E);
    block_reduce<<<nBlk, 256, 0, stream>>>(cnt, bsum, N);
    scan_bsums<<<1, 256, 0, stream>>>(bsum, nBlk);
    write_rp<<<nBlk, 256, 0, stream>>>(cnt, bsum, rp, dinv, tail, N, E);
    if (nbuck <= 256 && N <= 65536) {
        bin_pairs<<<nbuck, 256, 0, stream>>>(src, dst, tail, pairs, E, nbuck);
        csr_fill<<<nbuck, 256, 0, stream>>>(pairs, rp, col, N);
    } else {
        fill_kernel<<<(E + 255) / 256, 256, 0, stream>>>(src, dst, rp, fill, col, E);
    }

    // prep (weights + dinv-scaled x cast, one launch)
    int prepElems = 188416 + N * 64;
    prep_all<<<(prepElems + 255) / 256, 256, 0, stream>>>(
        W1, W2, W3, lW1, x, dinv, Wt1, Wt2, Wt3, lW1_bf, xs0, N * 64);

    int gemmBlocks = (N + 127) / 128;
    int aggBlocks  = (N + 3) / 4;

    // conv1: aggregate first (64-dim bf16), then GEMM with bias epilogue
    aggregate64<<<aggBlocks, 256, 0, stream>>>(xs0, rp, col, dinv, ax, N);
    mfma_gemm<1, bf16><<<dim3(gemmBlocks, 1), 256, 0, stream>>>(
        ax, 64, 64, Wt1, b1, nullptr, hcat + 0, 384, N);
    // conv2: GEMM -> fp8 xw (rows pre-scaled by dinv), aggregate fp8 (+bias)
    mfma_gemm<0, fp8s><<<dim3(gemmBlocks, 1), 256, 0, stream>>>(
        hcat + 0, 384, 128, Wt2, nullptr, dinv, xw8, 128, N);
    aggregate_fp8<<<aggBlocks, 256, 0, stream>>>(xw8, rp, col, dinv, b2, hcat + 128, 384, N);
    // conv3
    mfma_gemm<0, fp8s><<<dim3(gemmBlocks, 1), 256, 0, stream>>>(
        hcat + 128, 384, 128, Wt3, nullptr, dinv, xw8, 128, N);
    aggregate_fp8<<<aggBlocks, 256, 0, stream>>>(xw8, rp, col, dinv, b3, hcat + 256, 384, N);

    // MLP head
    mfma_gemm<2, bf16><<<dim3(gemmBlocks, 3), 256, 0, stream>>>(
        hcat, 384, 384, lW1_bf, lb1, nullptr, hrel, 384, N);
    linear2_softmax<<<(N + 3) / 4, 256, 0, stream>>>(hrel, lW2, lb2, out, N);
}

// Round 8
// 279.215 us; speedup vs baseline: 3.0543x; 1.1399x over previous
//
#include <hip/hip_runtime.h>
#include <hip/hip_bf16.h>
#include <hip/hip_fp8.h>
#include <cmath>

// ---------------------------------------------------------------------------
// Round 8:
//   - Pair-gather aggregates: two edges per VMEM instruction (32-lane halves,
//     4 B/lane), __shfl broadcast of edge ids, __shfl_xor(32) cross-half
//     combine. Halves gather instruction count vs R7.
//   - Compact CSR build: bucket_hist (LDS hist, no 850k global atomics) ->
//     scan_tails -> bin_pairs -> csr_fill_full (derives per-node counts, rp,
//     dinv from pairs in LDS; all writes coalesced). 7 -> 5 dispatches.
//   - (R7) fp8 e4m3 xw for conv2/3 gathers; (R5/R6) binned build, readlane
//     aggregation; bf16 MFMA 128x128/BK32 GEMMs, global_load_lds w16.
// ---------------------------------------------------------------------------

typedef __bf16 bf16;
typedef __bf16 bf16x2 __attribute__((ext_vector_type(2)));
typedef __bf16 bf16x8 __attribute__((ext_vector_type(8)));
typedef float  f32x4  __attribute__((ext_vector_type(4)));
typedef unsigned char fp8s;   // e4m3 storage byte

__device__ __forceinline__ void load_lds16(const bf16* g, bf16* l) {
    __builtin_amdgcn_global_load_lds(
        (const __attribute__((address_space(1))) void*)g,
        (__attribute__((address_space(3))) void*)l, 16, 0, 0);
}

__device__ __forceinline__ bf16 convert_out(float v, bf16*) { return (bf16)v; }
__device__ __forceinline__ fp8s convert_out(float v, fp8s*) {
    __hip_fp8_e4m3 q(v); return (fp8s)q.__x;
}

__device__ __forceinline__ float4 fp8x4_to_f4(unsigned int p) {
    __hip_fp8x2_e4m3 lo, hi;
    lo.__x = (__hip_fp8x2_storage_t)(p & 0xffffu);
    hi.__x = (__hip_fp8x2_storage_t)(p >> 16);
    float2 a = (float2)lo, c = (float2)hi;
    return make_float4(a.x, a.y, c.x, c.y);
}

// ---------------- CSR build (bucketed, N <= 65536 path) ----------------

// 196 bucket counts (dst>>8) via LDS histogram
__launch_bounds__(256)
__global__ void bucket_hist(const int* __restrict__ dst, int* __restrict__ bcnt, int e) {
    __shared__ int h[256];
    int t = threadIdx.x;
    h[t] = 0;
    __syncthreads();
    for (int i = blockIdx.x * 256 + t; i < e; i += gridDim.x * 256)
        atomicAdd(&h[dst[i] >> 8], 1);
    __syncthreads();
    if (h[t]) atomicAdd(&bcnt[t], h[t]);
}

// exclusive scan of bucket counts -> tailA (mutable) + bbase (stable, +1 entry)
__launch_bounds__(256)
__global__ void scan_tails(const int* __restrict__ bcnt, int* __restrict__ tailA,
                           int* __restrict__ bbase, int nbuck, int etot) {
    __shared__ int s[256];
    int t = threadIdx.x;
    int v = (t < nbuck) ? bcnt[t] : 0;
    s[t] = v;
    __syncthreads();
#pragma unroll
    for (int off = 1; off < 256; off <<= 1) {
        int tmp = (t >= off) ? s[t - off] : 0;
        __syncthreads();
        s[t] += tmp;
        __syncthreads();
    }
    int excl = s[t] - v;
    if (t < nbuck) { tailA[t] = excl; bbase[t] = excl; }
    if (t == 0) bbase[nbuck] = etot;
}

// bin edges by dst>>8 into per-bucket regions of `pairs`.
// Packed u32 = src | (dst&255)<<16 (requires N <= 65536).
__launch_bounds__(256)
__global__ void bin_pairs(const int* __restrict__ src, const int* __restrict__ dst,
                          int* __restrict__ tail, unsigned int* __restrict__ pairs,
                          int e, int nbuck) {
    __shared__ int hist[256], base[256], cur[256];
    int t = threadIdx.x;
    hist[t] = 0; cur[t] = 0;
    __syncthreads();
    int perBlock = (e + gridDim.x - 1) / gridDim.x;
    int lo = blockIdx.x * perBlock;
    int hi = lo + perBlock; if (hi > e) hi = e;
    for (int i = lo + t; i < hi; i += 256)
        atomicAdd(&hist[dst[i] >> 8], 1);
    __syncthreads();
    if (t < nbuck && hist[t] > 0) base[t] = atomicAdd(&tail[t], hist[t]);
    __syncthreads();
    for (int i = lo + t; i < hi; i += 256) {
        int d = dst[i];
        int b = d >> 8;
        int r = atomicAdd(&cur[b], 1);
        pairs[base[b] + r] = (unsigned)src[i] | ((unsigned)(d & 255) << 16);
    }
}

// one block per bucket: per-node counts from pairs (LDS hist), local scan ->
// rp + dinv; then LDS-window scatter -> coalesced col write.
#define FILL_CAP 6144
__launch_bounds__(256)
__global__ void csr_fill_full(const unsigned int* __restrict__ pairs,
                              const int* __restrict__ bbase,
                              int* __restrict__ rp, float* __restrict__ dinv,
                              int* __restrict__ col, int n, int etot) {
    __shared__ int cnt[256];
    __shared__ int ofs[256];
    __shared__ int ss[256];
    __shared__ int win[FILL_CAP];
    int b = blockIdx.x, t = threadIdx.x;
    int nodeBase = b << 8;
    int lo = bbase[b];
    int bcountE = bbase[b + 1] - lo;
    cnt[t] = 0;
    __syncthreads();
    for (int i = t; i < bcountE; i += 256)
        atomicAdd(&cnt[pairs[lo + i] >> 16], 1);
    __syncthreads();
    int myc = cnt[t];
    ss[t] = myc;
    __syncthreads();
#pragma unroll
    for (int off = 1; off < 256; off <<= 1) {
        int tmp = (t >= off) ? ss[t - off] : 0;
        __syncthreads();
        ss[t] += tmp;
        __syncthreads();
    }
    int excl = ss[t] - myc;
    ofs[t] = excl;
    int node = nodeBase + t;
    if (node < n) {
        rp[node]   = lo + excl;
        dinv[node] = rsqrtf((float)(myc + 1));    // +1 self-loop
        if (node == n - 1) rp[n] = etot;
    }
    cnt[t] = 0;
    __syncthreads();
    if (bcountE <= FILL_CAP) {
        for (int i = t; i < bcountE; i += 256) {
            unsigned p = pairs[lo + i];
            int dl = (int)(p >> 16);
            int r = atomicAdd(&cnt[dl], 1);
            win[ofs[dl] + r] = (int)(p & 0xffffu);
        }
        __syncthreads();
        for (int i = t; i < bcountE; i += 256) col[lo + i] = win[i];
    } else {   // overflow fallback (never taken for random graphs)
        for (int i = t; i < bcountE; i += 256) {
            unsigned p = pairs[lo + i];
            int dl = (int)(p >> 16);
            int r = atomicAdd(&cnt[dl], 1);
            col[lo + ofs[dl] + r] = (int)(p & 0xffffu);
        }
    }
}

// -------- fallback CSR build for N > 65536 (not used at this size) --------

__launch_bounds__(256)
__global__ void init_kernel(int* __restrict__ cnt, int* __restrict__ fill, int n) {
    int i = blockIdx.x * 256 + threadIdx.x;
    if (i < n) { cnt[i] = 1; fill[i] = 0; }
}

__launch_bounds__(256)
__global__ void hist_kernel(const int* __restrict__ dst, int* __restrict__ cnt, int e) {
    int i = blockIdx.x * 256 + threadIdx.x;
    if (i < e) atomicAdd(&cnt[dst[i]], 1);
}

__launch_bounds__(256)
__global__ void block_reduce(const int* __restrict__ cnt, int* __restrict__ bsum, int n) {
    __shared__ int s[256];
    int t = threadIdx.x;
    int i = blockIdx.x * 256 + t;
    int v = (i < n) ? cnt[i] - 1 : 0;
    s[t] = v;
    __syncthreads();
#pragma unroll
    for (int off = 128; off > 0; off >>= 1) {
        if (t < off) s[t] += s[t + off];
        __syncthreads();
    }
    if (t == 0) bsum[blockIdx.x] = s[0];
}

__launch_bounds__(256)
__global__ void scan_bsums(int* __restrict__ bsum, int nb) {
    __shared__ int s[256];
    int t = threadIdx.x;
    int v = (t < nb) ? bsum[t] : 0;
    s[t] = v;
    __syncthreads();
#pragma unroll
    for (int off = 1; off < 256; off <<= 1) {
        int tmp = (t >= off) ? s[t - off] : 0;
        __syncthreads();
        s[t] += tmp;
        __syncthreads();
    }
    if (t < nb) bsum[t] = s[t] - v;
}

__launch_bounds__(256)
__global__ void write_rp(const int* __restrict__ cnt, const int* __restrict__ bsum,
                         int* __restrict__ rp, float* __restrict__ dinv, int n, int etot) {
    __shared__ int s[256];
    int t = threadIdx.x;
    int i = blockIdx.x * 256 + t;
    int c = (i < n) ? cnt[i] : 1;
    int v = c - 1;
    s[t] = v;
    __syncthreads();
#pragma unroll
    for (int off = 1; off < 256; off <<= 1) {
        int tmp = (t >= off) ? s[t - off] : 0;
        __syncthreads();
        s[t] += tmp;
        __syncthreads();
    }
    if (i < n) {
        rp[i]   = bsum[blockIdx.x] + s[t] - v;
        dinv[i] = rsqrtf((float)c);
        if (i == n - 1) rp[n] = etot;
    }
}

__launch_bounds__(256)
__global__ void fill_kernel(const int* __restrict__ src, const int* __restrict__ dst,
                            const int* __restrict__ rp, int* __restrict__ fill,
                            int* __restrict__ col, int e) {
    int i = blockIdx.x * 256 + threadIdx.x;
    if (i < e) {
        int d = dst[i];
        int pos = rp[d] + atomicAdd(&fill[d], 1);
        col[pos] = src[i];
    }
}

// ---------------- prep (fused) ----------------
__launch_bounds__(256)
__global__ void prep_all(const float* __restrict__ W1, const float* __restrict__ W2,
                         const float* __restrict__ W3, const float* __restrict__ lW1,
                         const float* __restrict__ x, const float* __restrict__ dinv,
                         bf16* __restrict__ Wt1, bf16* __restrict__ Wt2,
                         bf16* __restrict__ Wt3, bf16* __restrict__ lW1_bf,
                         bf16* __restrict__ xs0, int n64) {
    int i = blockIdx.x * 256 + threadIdx.x;
    if (i < 8192) {
        int k = i >> 7, c = i & 127; Wt1[c * 64 + k] = (bf16)W1[i];
    } else if (i < 24576) {
        int j = i - 8192; int k = j >> 7, c = j & 127; Wt2[c * 128 + k] = (bf16)W2[j];
    } else if (i < 40960) {
        int j = i - 24576; int k = j >> 7, c = j & 127; Wt3[c * 128 + k] = (bf16)W3[j];
    } else if (i < 188416) {
        int j = i - 40960; lW1_bf[j] = (bf16)lW1[j];
    } else {
        int j = i - 188416;
        if (j < n64) xs0[j] = (bf16)(x[j] * dinv[j >> 6]);
    }
}

// ---------------- MFMA GEMM ----------------
template<int EPI, typename OutT>
__launch_bounds__(256, 4)
__global__ void mfma_gemm(const bf16* __restrict__ A, int strideA, int K,
                          const bf16* __restrict__ Bt,
                          const float* __restrict__ bias,
                          const float* __restrict__ rowScale,
                          OutT* __restrict__ C, int strideC, int n) {
    __shared__ bf16 As[128 * 32];
    __shared__ bf16 Bs[128 * 32];
    int t = threadIdx.x;
    int rowBase = blockIdx.x * 128;
    int colBase = blockIdx.y * 128;

    int lane = t & 63;
    int wv   = t >> 6;
    int wr   = wv >> 1, wc = wv & 1;
    int ml   = lane & 15, quad = lane >> 4;

    f32x4 acc[4][4];
#pragma unroll
    for (int i = 0; i < 4; ++i)
#pragma unroll
        for (int j = 0; j < 4; ++j) acc[i][j] = (f32x4){0.f, 0.f, 0.f, 0.f};

    int srow0 = wv * 32 + (lane >> 2);
    int cchunk = lane & 3;

    for (int kt = 0; kt < K; kt += 32) {
        __syncthreads();
#pragma unroll
        for (int inst = 0; inst < 2; ++inst) {
            int r  = srow0 + inst * 16;
            int gc = (cchunk ^ (r & 3)) * 8;
            int gr = rowBase + r; if (gr >= n) gr = n - 1;
            load_lds16(A + (size_t)gr * strideA + kt + gc,
                       &As[(wv * 128 + inst * 64) * 8]);
            int br = colBase + r;
            load_lds16(Bt + (size_t)br * K + kt + gc,
                       &Bs[(wv * 128 + inst * 64) * 8]);
        }
        __syncthreads();
        bf16x8 af[4], bfv[4];
#pragma unroll
        for (int i = 0; i < 4; ++i) {
            int ra = wr * 64 + i * 16 + ml;
            int rb = wc * 64 + i * 16 + ml;
            af[i]  = *(const bf16x8*)&As[(ra * 4 + (quad ^ (ra & 3))) * 8];
            bfv[i] = *(const bf16x8*)&Bs[(rb * 4 + (quad ^ (rb & 3))) * 8];
        }
#pragma unroll
        for (int i = 0; i < 4; ++i)
#pragma unroll
            for (int j = 0; j < 4; ++j)
                acc[i][j] = __builtin_amdgcn_mfma_f32_16x16x32_bf16(
                    af[i], bfv[j], acc[i][j], 0, 0, 0);
    }

#pragma unroll
    for (int i = 0; i < 4; ++i) {
#pragma unroll
        for (int reg = 0; reg < 4; ++reg) {
            int gr = rowBase + wr * 64 + i * 16 + quad * 4 + reg;
            if (gr < n) {
                float sc = (EPI == 0 && rowScale) ? rowScale[gr] : 1.f;
#pragma unroll
                for (int j = 0; j < 4; ++j) {
                    int gc = colBase + wc * 64 + j * 16 + ml;
                    float v = acc[i][j][reg];
                    if (EPI >= 1) v += bias[gc];
                    if (EPI == 2) v = fmaxf(v, 0.f);
                    C[(size_t)gr * strideC + gc] = convert_out(v * sc, (OutT*)nullptr);
                }
            }
        }
    }
}

// ---------------- aggregation (pair-gather) ----------------
// Wave = 1 node; two 32-lane halves each gather a DIFFERENT edge per VMEM
// instruction (4 B/lane x 64 = 256 B = 2 rows). Edge ids via __shfl
// (bpermute); halves combined with __shfl_xor(32); self-loop/bias/scale after.

// 64-dim bf16 rows (conv1 input): lane32 covers cols [lane32*2, +2).
__launch_bounds__(256)
__global__ void aggregate64(const bf16* __restrict__ xs, const int* __restrict__ rp,
                            const int* __restrict__ col, const float* __restrict__ dinv,
                            bf16* __restrict__ out, int n) {
    int gid  = blockIdx.x * 256 + threadIdx.x;
    int v    = gid >> 6;
    int lane = gid & 63;
    if (v >= n) return;
    int lane32 = lane & 31;
    int half   = lane >> 5;
    float di = dinv[v];
    int b = rp[v], e = rp[v + 1];
    int deg = e - b;
    const bf16* base = xs + lane32 * 2;
    float ax = 0.f, ay = 0.f;
    for (int j0 = 0; j0 < deg; j0 += 64) {
        int rem = deg - j0; if (rem > 64) rem = 64;
        int cj = (lane < rem) ? col[b + j0 + lane] : 0;
        int jj = 0;
        for (; jj + 8 <= rem; jj += 8) {
            int s0 = __shfl(cj, jj + 0 + half, 64);
            int s1 = __shfl(cj, jj + 2 + half, 64);
            int s2 = __shfl(cj, jj + 4 + half, 64);
            int s3 = __shfl(cj, jj + 6 + half, 64);
            bf16x2 m0 = *(const bf16x2*)(base + (size_t)s0 * 64);
            bf16x2 m1 = *(const bf16x2*)(base + (size_t)s1 * 64);
            bf16x2 m2 = *(const bf16x2*)(base + (size_t)s2 * 64);
            bf16x2 m3 = *(const bf16x2*)(base + (size_t)s3 * 64);
            ax += ((float)m0[0] + (float)m1[0]) + ((float)m2[0] + (float)m3[0]);
            ay += ((float)m0[1] + (float)m1[1]) + ((float)m2[1] + (float)m3[1]);
        }
        for (; jj + 2 <= rem; jj += 2) {
            int s = __shfl(cj, jj + half, 64);
            bf16x2 m = *(const bf16x2*)(base + (size_t)s * 64);
            ax += (float)m[0]; ay += (float)m[1];
        }
        if (jj < rem) {        // single leftover edge -> half0 only
            int s = __shfl(cj, jj, 64);
            bf16x2 m = *(const bf16x2*)(base + (size_t)s * 64);
            if (half == 0) { ax += (float)m[0]; ay += (float)m[1]; }
        }
    }
    ax += __shfl_xor(ax, 32, 64);
    ay += __shfl_xor(ay, 32, 64);
    bf16x2 mv = *(const bf16x2*)(base + (size_t)v * 64);
    ax = di * (ax + (float)mv[0]);
    ay = di * (ay + (float)mv[1]);
    if (half == 0) {
        bf16x2 o; o[0] = (bf16)ax; o[1] = (bf16)ay;
        *(bf16x2*)(out + (size_t)v * 64 + lane32 * 2) = o;
    }
}

// 128-dim fp8 rows: lane32 covers cols [lane32*4, +4).
__launch_bounds__(256)
__global__ void aggregate_fp8(const fp8s* __restrict__ xs, const int* __restrict__ rp,
                              const int* __restrict__ col, const float* __restrict__ dinv,
                              const float* __restrict__ bias, bf16* __restrict__ out,
                              int outStride, int n) {
    int gid  = blockIdx.x * 256 + threadIdx.x;
    int v    = gid >> 6;
    int lane = gid & 63;
    if (v >= n) return;
    int lane32 = lane & 31;
    int half   = lane >> 5;
    float di = dinv[v];
    int b = rp[v], e = rp[v + 1];
    int deg = e - b;
    const fp8s* base = xs + lane32 * 4;
    float a0 = 0.f, a1 = 0.f, a2 = 0.f, a3 = 0.f;
    for (int j0 = 0; j0 < deg; j0 += 64) {
        int rem = deg - j0; if (rem > 64) rem = 64;
        int cj = (lane < rem) ? col[b + j0 + lane] : 0;
        int jj = 0;
        for (; jj + 8 <= rem; jj += 8) {
            int s0 = __shfl(cj, jj + 0 + half, 64);
            int s1 = __shfl(cj, jj + 2 + half, 64);
            int s2 = __shfl(cj, jj + 4 + half, 64);
            int s3 = __shfl(cj, jj + 6 + half, 64);
            unsigned p0 = *(const unsigned*)(base + (size_t)s0 * 128);
            unsigned p1 = *(const unsigned*)(base + (size_t)s1 * 128);
            unsigned p2 = *(const unsigned*)(base + (size_t)s2 * 128);
            unsigned p3 = *(const unsigned*)(base + (size_t)s3 * 128);
            float4 f0 = fp8x4_to_f4(p0), f1 = fp8x4_to_f4(p1);
            float4 f2 = fp8x4_to_f4(p2), f3 = fp8x4_to_f4(p3);
            a0 += (f0.x + f1.x) + (f2.x + f3.x);
            a1 += (f0.y + f1.y) + (f2.y + f3.y);
            a2 += (f0.z + f1.z) + (f2.z + f3.z);
            a3 += (f0.w + f1.w) + (f2.w + f3.w);
        }
        for (; jj + 2 <= rem; jj += 2) {
            int s = __shfl(cj, jj + half, 64);
            float4 f = fp8x4_to_f4(*(const unsigned*)(base + (size_t)s * 128));
            a0 += f.x; a1 += f.y; a2 += f.z; a3 += f.w;
        }
        if (jj < rem) {        // single leftover edge -> half0 only
            int s = __shfl(cj, jj, 64);
            float4 f = fp8x4_to_f4(*(const unsigned*)(base + (size_t)s * 128));
            if (half == 0) { a0 += f.x; a1 += f.y; a2 += f.z; a3 += f.w; }
        }
    }
    a0 += __shfl_xor(a0, 32, 64);
    a1 += __shfl_xor(a1, 32, 64);
    a2 += __shfl_xor(a2, 32, 64);
    a3 += __shfl_xor(a3, 32, 64);
    float4 fv = fp8x4_to_f4(*(const unsigned*)(base + (size_t)v * 128));
    a0 = di * (a0 + fv.x);
    a1 = di * (a1 + fv.y);
    a2 = di * (a2 + fv.z);
    a3 = di * (a3 + fv.w);
    if (half == 0) {
        float4 bb = *(const float4*)(bias + lane32 * 4);
        bf16 o0 = (bf16)(a0 + bb.x), o1 = (bf16)(a1 + bb.y);
        bf16 o2 = (bf16)(a2 + bb.z), o3 = (bf16)(a3 + bb.w);
        bf16* op = out + (size_t)v * outStride + lane32 * 4;
        op[0] = o0; op[1] = o1; op[2] = o2; op[3] = o3;
    }
}

// ---------------- linear2 + softmax ----------------
__launch_bounds__(256)
__global__ void linear2_softmax(const bf16* __restrict__ hrel, const float* __restrict__ lW2,
                                const float* __restrict__ lb2, float* __restrict__ out, int n) {
    int gid  = blockIdx.x * 256 + threadIdx.x;
    int node = gid >> 6;
    int lane = gid & 63;
    if (node >= n) return;
    const bf16* h = hrel + (size_t)node * 384;
    float a0 = 0.f, a1 = 0.f;
#pragma unroll
    for (int j = 0; j < 6; ++j) {
        int k = lane + j * 64;
        float hv = (float)h[k];
        a0 += hv * lW2[k];
        a1 += hv * lW2[384 + k];
    }
#pragma unroll
    for (int off = 32; off > 0; off >>= 1) {
        a0 += __shfl_down(a0, off, 64);
        a1 += __shfl_down(a1, off, 64);
    }
    if (lane == 0) {
        float l0 = a0 + lb2[0], l1 = a1 + lb2[1];
        out[(size_t)node * 2 + 0] = l0;
        out[(size_t)node * 2 + 1] = l1;
        float m  = fmaxf(l0, l1);
        float e0 = expf(l0 - m), e1 = expf(l1 - m);
        float inv = 1.f / (e0 + e1);
        out[(size_t)(n + node) * 2 + 0] = e0 * inv;
        out[(size_t)(n + node) * 2 + 1] = e1 * inv;
    }
}

extern "C" void kernel_launch(void* const* d_in, const int* in_sizes, int n_in,
                              void* d_out, int out_size, void* d_ws, size_t ws_size,
                              hipStream_t stream) {
    const float* x   = (const float*)d_in[0];
    const int*   ei  = (const int*)d_in[1];
    const float* W1  = (const float*)d_in[2];
    const float* b1  = (const float*)d_in[3];
    const float* W2  = (const float*)d_in[4];
    const float* b2  = (const float*)d_in[5];
    const float* W3  = (const float*)d_in[6];
    const float* b3  = (const float*)d_in[7];
    const float* lW1 = (const float*)d_in[8];
    const float* lb1 = (const float*)d_in[9];
    const float* lW2 = (const float*)d_in[10];
    const float* lb2 = (const float*)d_in[11];
    float* out = (float*)d_out;

    int N = in_sizes[0] / 64;
    int E = in_sizes[1] / 2;
    const int* src = ei;
    const int* dst = ei + E;

    char* ws = (char*)d_ws;
    size_t off = 0;
    auto take = [&](size_t bytes) -> char* {
        char* p = ws + off;
        off += (bytes + 255) & ~(size_t)255;
        return p;
    };
    int nBlk  = (N + 255) / 256;
    int nbuck = nBlk;
    int*   cnt    = (int*)take((size_t)N * 4);         // fallback only
    int*   fill   = (int*)take((size_t)N * 4);         // fallback only
    int*   rp     = (int*)take((size_t)(N + 1) * 4);
    float* dinv   = (float*)take((size_t)N * 4);
    int*   bsum   = (int*)take((size_t)nBlk * 4);      // fallback only
    int*   bcnt   = (int*)take((size_t)nbuck * 4);
    int*   tailA  = (int*)take((size_t)nbuck * 4);
    int*   bbase  = (int*)take((size_t)(nbuck + 1) * 4);
    int*   col    = (int*)take((size_t)E * 4);
    unsigned int* pairs = (unsigned int*)take((size_t)E * 4);
    bf16*  xs0    = (bf16*)take((size_t)N * 64 * 2);
    bf16*  ax     = (bf16*)take((size_t)N * 64 * 2);
    bf16*  Wt1    = (bf16*)take((size_t)64 * 128 * 2);
    bf16*  Wt2    = (bf16*)take((size_t)128 * 128 * 2);
    bf16*  Wt3    = (bf16*)take((size_t)128 * 128 * 2);
    bf16*  lW1_bf = (bf16*)take((size_t)384 * 384 * 2);
    fp8s*  xw8    = (fp8s*)take((size_t)N * 128);
    bf16*  hcat   = (bf16*)take((size_t)N * 384 * 2);
    bf16*  hrel   = (bf16*)take((size_t)N * 384 * 2);

    // CSR build
    if (nbuck <= 256 && N <= 65536) {
        hipMemsetAsync(bcnt, 0, (size_t)nbuck * 4, stream);
        bucket_hist<<<256, 256, 0, stream>>>(dst, bcnt, E);
        scan_tails<<<1, 256, 0, stream>>>(bcnt, tailA, bbase, nbuck, E);
        bin_pairs<<<nbuck, 256, 0, stream>>>(src, dst, tailA, pairs, E, nbuck);
        csr_fill_full<<<nbuck, 256, 0, stream>>>(pairs, bbase, rp, dinv, col, N, E);
    } else {
        init_kernel<<<nBlk, 256, 0, stream>>>(cnt, fill, N);
        hist_kernel<<<(E + 255) / 256, 256, 0, stream>>>(dst, cnt, E);
        block_reduce<<<nBlk, 256, 0, stream>>>(cnt, bsum, N);
        scan_bsums<<<1, 256, 0, stream>>>(bsum, nBlk);
        write_rp<<<nBlk, 256, 0, stream>>>(cnt, bsum, rp, dinv, N, E);
        fill_kernel<<<(E + 255) / 256, 256, 0, stream>>>(src, dst, rp, fill, col, E);
    }

    // prep (weights + dinv-scaled x cast, one launch)
    int prepElems = 188416 + N * 64;
    prep_all<<<(prepElems + 255) / 256, 256, 0, stream>>>(
        W1, W2, W3, lW1, x, dinv, Wt1, Wt2, Wt3, lW1_bf, xs0, N * 64);

    int gemmBlocks = (N + 127) / 128;
    int aggBlocks  = (N + 3) / 4;

    // conv1: aggregate first (64-dim bf16), then GEMM with bias epilogue
    aggregate64<<<aggBlocks, 256, 0, stream>>>(xs0, rp, col, dinv, ax, N);
    mfma_gemm<1, bf16><<<dim3(gemmBlocks, 1), 256, 0, stream>>>(
        ax, 64, 64, Wt1, b1, nullptr, hcat + 0, 384, N);
    // conv2: GEMM -> fp8 xw (rows pre-scaled by dinv), aggregate fp8 (+bias)
    mfma_gemm<0, fp8s><<<dim3(gemmBlocks, 1), 256, 0, stream>>>(
        hcat + 0, 384, 128, Wt2, nullptr, dinv, xw8, 128, N);
    aggregate_fp8<<<aggBlocks, 256, 0, stream>>>(xw8, rp, col, dinv, b2, hcat + 128, 384, N);
    // conv3
    mfma_gemm<0, fp8s><<<dim3(gemmBlocks, 1), 256, 0, stream>>>(
        hcat + 128, 384, 128, Wt3, nullptr, dinv, xw8, 128, N);
    aggregate_fp8<<<aggBlocks, 256, 0, stream>>>(xw8, rp, col, dinv, b3, hcat + 256, 384, N);

    // MLP head
    mfma_gemm<2, bf16><<<dim3(gemmBlocks, 3), 256, 0, stream>>>(
        hcat, 384, 384, lW1_bf, lb1, nullptr, hrel, 384, N);
    linear2_softmax<<<(N + 3) / 4, 256, 0, stream>>>(hrel, lW2, lb2, out, N);
}